// Round 2
// baseline (1375.586 us; speedup 1.0000x reference)
//
#include <hip/hip_runtime.h>
#include <hip/hip_bf16.h>

// ---------------------------------------------------------------------------
// GraphEncoder: SAGE(6->1024) -> LN -> ReLU -> SAGE(1024->1024) -> LN -> ReLU
//   -> concat(Fourier feats) -> per-graph mean pool -> FC(2048->256) -> LN
// Scratch lives in __device__ globals (d_ws size is unknown; 300MB needed).
// ---------------------------------------------------------------------------

#define N_NODES 50000
#define N_EDGES 500000
#define N_GRAPHS 64
#define IN_DIM 6
#define GNN_DIM 1024
#define OUT_DIM 256
#define CAT_DIM 2048
#define M_PAD 50048   // 391 * 128

typedef __attribute__((ext_vector_type(8))) short short8;
typedef __attribute__((ext_vector_type(4))) float f32x4;

// ---------------- static device scratch (allocated at module load) ---------
__device__ int g_cnt[N_NODES + 1];
__device__ int g_cursor[N_NODES];
__device__ int g_gcnt[N_GRAPHS];
__device__ int g_rowptr[N_NODES + 1];
__device__ int g_goff[N_GRAPHS + 1];
__device__ int g_esrc[N_EDGES];
__device__ unsigned short g_w2lt[(size_t)GNN_DIM * GNN_DIM];
__device__ unsigned short g_w2rt[(size_t)GNN_DIM * GNN_DIM];
__device__ float g_agg1[(size_t)N_NODES * IN_DIM];
__device__ unsigned short g_h[(size_t)M_PAD * GNN_DIM];
__device__ unsigned short g_agg2[(size_t)M_PAD * GNN_DIM];
__device__ unsigned short g_h2[(size_t)M_PAD * GNN_DIM];
__device__ float g_gpool[(size_t)N_GRAPHS * CAT_DIM];

__device__ __forceinline__ float bflo(int u) { return __uint_as_float(((unsigned)u) << 16); }
__device__ __forceinline__ float bfhi(int u) { return __uint_as_float(((unsigned)u) & 0xffff0000u); }
__device__ __forceinline__ unsigned short f2bf(float f) {
    unsigned u = __float_as_uint(f);
    unsigned rounded = u + 0x7fff + ((u >> 16) & 1);   // RNE
    return (unsigned short)(rounded >> 16);
}

// ---------------------------------------------------------------------------
// CSR build
// ---------------------------------------------------------------------------
__global__ void zero_kernel() {
    int i = blockIdx.x * 256 + threadIdx.x;
    if (i <= N_NODES) g_cnt[i] = 0;
    if (i < N_NODES) g_cursor[i] = 0;
    if (i < N_GRAPHS) g_gcnt[i] = 0;
}

__global__ void count_kernel(const int* __restrict__ dst, const int* __restrict__ batch) {
    int i = blockIdx.x * 256 + threadIdx.x;
    if (i < N_EDGES) atomicAdd(&g_cnt[dst[i]], 1);
    if (i < N_NODES) atomicAdd(&g_gcnt[batch[i]], 1);
}

__global__ __launch_bounds__(1024) void scan_kernel() {
    __shared__ int sdata[1024];
    __shared__ int carry;
    int t = threadIdx.x;
    if (t == 0) carry = 0;
    __syncthreads();
    for (int base = 0; base < N_NODES; base += 1024) {
        int v = (base + t < N_NODES) ? g_cnt[base + t] : 0;
        sdata[t] = v;
        __syncthreads();
        for (int off = 1; off < 1024; off <<= 1) {
            int add = (t >= off) ? sdata[t - off] : 0;
            __syncthreads();
            sdata[t] += add;
            __syncthreads();
        }
        if (base + t < N_NODES) g_rowptr[base + t] = carry + sdata[t] - v;  // exclusive
        __syncthreads();
        if (t == 0) carry += sdata[1023];
        __syncthreads();
    }
    if (t == 0) g_rowptr[N_NODES] = carry;
}

__global__ void goff_kernel() {
    if (threadIdx.x == 0 && blockIdx.x == 0) {
        int acc = 0;
        for (int g = 0; g < N_GRAPHS; ++g) { g_goff[g] = acc; acc += g_gcnt[g]; }
        g_goff[N_GRAPHS] = acc;
    }
}

__global__ void scatter_kernel(const int* __restrict__ src, const int* __restrict__ dst) {
    int e = blockIdx.x * 256 + threadIdx.x;
    if (e >= N_EDGES) return;
    int d = dst[e];
    int pos = atomicAdd(&g_cursor[d], 1);
    g_esrc[g_rowptr[d] + pos] = src[e];
}

// ---------------------------------------------------------------------------
// Weight transpose f32 [K][N] -> bf16 [N][K]
// ---------------------------------------------------------------------------
__global__ void transpose_bf16(const float* __restrict__ W, unsigned short* __restrict__ Wt) {
    __shared__ float tile[32][33];
    int bx = blockIdx.x & 31, by = blockIdx.x >> 5;
    int tx = threadIdx.x & 31, ty = threadIdx.x >> 5;  // 32x8
    for (int i = 0; i < 32; i += 8)
        tile[ty + i][tx] = W[(size_t)(by * 32 + ty + i) * GNN_DIM + bx * 32 + tx];
    __syncthreads();
    for (int i = 0; i < 32; i += 8)
        Wt[(size_t)(bx * 32 + ty + i) * GNN_DIM + by * 32 + tx] = f2bf(tile[tx][ty + i]);
}

// ---------------------------------------------------------------------------
// Layer 1: mean-agg of x (6-dim), transform, LN, ReLU -> h (bf16)
// ---------------------------------------------------------------------------
__global__ void l1_agg_kernel(const float* __restrict__ x) {
    int id = blockIdx.x * 256 + threadIdx.x;
    int n = id >> 3, slot = id & 7;
    if (n >= N_NODES || slot >= IN_DIM) return;
    int beg = g_rowptr[n], end = g_rowptr[n + 1];
    float s = 0.f;
    for (int i = beg; i < end; ++i) s += x[(size_t)g_esrc[i] * IN_DIM + slot];
    g_agg1[n * IN_DIM + slot] = s / (float)max(end - beg, 1);
}

__global__ __launch_bounds__(256) void l1_transform_kernel(
        const float* __restrict__ x,
        const float* __restrict__ W1l, const float* __restrict__ b1,
        const float* __restrict__ W1r, const float* __restrict__ g1,
        const float* __restrict__ be1) {
    int n = blockIdx.x, t = threadIdx.x;
    __shared__ float xa[IN_DIM], aa[IN_DIM];
    if (t < IN_DIM) { xa[t] = x[n * IN_DIM + t]; aa[t] = g_agg1[n * IN_DIM + t]; }
    __syncthreads();
    float v[4];
    #pragma unroll
    for (int j = 0; j < 4; ++j) {
        int d = t + j * 256;
        float s = b1[d];
        #pragma unroll
        for (int k = 0; k < IN_DIM; ++k)
            s += aa[k] * W1l[k * GNN_DIM + d] + xa[k] * W1r[k * GNN_DIM + d];
        v[j] = s;
    }
    float sum = v[0] + v[1] + v[2] + v[3];
    float sq  = v[0]*v[0] + v[1]*v[1] + v[2]*v[2] + v[3]*v[3];
    #pragma unroll
    for (int off = 32; off; off >>= 1) { sum += __shfl_xor(sum, off); sq += __shfl_xor(sq, off); }
    __shared__ float s1[4], s2[4];
    if ((t & 63) == 0) { s1[t >> 6] = sum; s2[t >> 6] = sq; }
    __syncthreads();
    sum = s1[0] + s1[1] + s1[2] + s1[3];
    sq  = s2[0] + s2[1] + s2[2] + s2[3];
    float mu = sum * (1.f / GNN_DIM);
    float var = sq * (1.f / GNN_DIM) - mu * mu;
    float rstd = rsqrtf(var + 1e-5f);
    #pragma unroll
    for (int j = 0; j < 4; ++j) {
        int d = t + j * 256;
        float y = (v[j] - mu) * rstd * g1[d] + be1[d];
        y = fmaxf(y, 0.f);
        g_h[(size_t)n * GNN_DIM + d] = f2bf(y);
    }
}

// ---------------------------------------------------------------------------
// Layer 2 aggregation: agg2[n] = mean of h[src] over incident edges
// ---------------------------------------------------------------------------
__global__ __launch_bounds__(256) void l2_agg_kernel() {
    int n = blockIdx.x, t = threadIdx.x;
    int beg = g_rowptr[n], end = g_rowptr[n + 1];
    float s0 = 0.f, s1 = 0.f, s2 = 0.f, s3 = 0.f;
    __shared__ int el[256];
    for (int base = beg; base < end; base += 256) {
        int m = min(256, end - base);
        if (t < m) el[t] = g_esrc[base + t];
        __syncthreads();
        for (int i = 0; i < m; ++i) {
            const int2* hr = (const int2*)(g_h + (size_t)el[i] * GNN_DIM);
            int2 w = hr[t];   // 4 bf16: dims 4t..4t+3
            s0 += bflo(w.x); s1 += bfhi(w.x); s2 += bflo(w.y); s3 += bfhi(w.y);
        }
        __syncthreads();
    }
    float inv = 1.f / (float)max(end - beg, 1);
    unsigned short* out = g_agg2 + (size_t)n * GNN_DIM + 4 * t;
    out[0] = f2bf(s0 * inv); out[1] = f2bf(s1 * inv);
    out[2] = f2bf(s2 * inv); out[3] = f2bf(s3 * inv);
}

// ---------------------------------------------------------------------------
// Layer 2 GEMM: h2 = agg2 @ W2_l + h @ W2_r + b2  (bf16 MFMA, m97 structure)
// ---------------------------------------------------------------------------
#define BM 128
#define BN 128
#define BK 64

__global__ __launch_bounds__(256) void gemm2_kernel(const float* __restrict__ bias) {
    __shared__ __attribute__((aligned(16))) unsigned short As[BM * BK];
    __shared__ __attribute__((aligned(16))) unsigned short Bs[BN * BK];
    const int nTilesN = GNN_DIM / BN;  // 8
    int bm = blockIdx.x / nTilesN, bn = blockIdx.x % nTilesN;
    int row0 = bm * BM, col0 = bn * BN;
    int t = threadIdx.x;
    int lane = t & 63, wid = t >> 6;
    int wr = wid >> 1, wc = wid & 1;     // 2x2 waves, each owns 64x64
    f32x4 acc[4][4] = {};
    for (int seg = 0; seg < 2; ++seg) {
        const unsigned short* A  = seg ? g_h : g_agg2;
        const unsigned short* Bt = seg ? g_w2rt : g_w2lt;
        for (int k0 = 0; k0 < GNN_DIM; k0 += BK) {
            __syncthreads();
            #pragma unroll
            for (int i = 0; i < 4; ++i) {
                int c = t + i * 256;
                int r = c >> 3, kk = (c & 7) * 8;
                __builtin_amdgcn_global_load_lds(
                    (const __attribute__((address_space(1))) void*)(A + (size_t)(row0 + r) * GNN_DIM + k0 + kk),
                    (__attribute__((address_space(3))) void*)(As + c * 8), 16, 0, 0);
            }
            #pragma unroll
            for (int i = 0; i < 4; ++i) {
                int c = t + i * 256;
                int r = c >> 3, kk = (c & 7) * 8;
                __builtin_amdgcn_global_load_lds(
                    (const __attribute__((address_space(1))) void*)(Bt + (size_t)(col0 + r) * GNN_DIM + k0 + kk),
                    (__attribute__((address_space(3))) void*)(Bs + c * 8), 16, 0, 0);
            }
            asm volatile("s_waitcnt vmcnt(0)" ::: "memory");
            __syncthreads();
            #pragma unroll
            for (int kk = 0; kk < BK; kk += 32) {
                short8 a[4], b[4];
                int krd = kk + (lane >> 4) * 8;
                #pragma unroll
                for (int m = 0; m < 4; ++m)
                    a[m] = *(const short8*)&As[(wr * 64 + m * 16 + (lane & 15)) * BK + krd];
                #pragma unroll
                for (int n = 0; n < 4; ++n)
                    b[n] = *(const short8*)&Bs[(wc * 64 + n * 16 + (lane & 15)) * BK + krd];
                #pragma unroll
                for (int m = 0; m < 4; ++m)
                    #pragma unroll
                    for (int n = 0; n < 4; ++n)
                        acc[m][n] = __builtin_amdgcn_mfma_f32_16x16x32_bf16(a[m], b[n], acc[m][n], 0, 0, 0);
            }
        }
    }
    #pragma unroll
    for (int m = 0; m < 4; ++m) {
        #pragma unroll
        for (int n = 0; n < 4; ++n) {
            int col = col0 + wc * 64 + n * 16 + (lane & 15);
            int rbase = row0 + wr * 64 + m * 16 + (lane >> 4) * 4;
            float bv = bias[col];
            #pragma unroll
            for (int r = 0; r < 4; ++r) {
                float v = acc[m][n][r] + bv;
                g_h2[(size_t)(rbase + r) * GNN_DIM + col] = f2bf(v);
            }
        }
    }
}

// ---------------------------------------------------------------------------
// Layer 2 LN + ReLU: hln = relu(LN(h2)*g2+be2)  (written back over g_agg2)
// ---------------------------------------------------------------------------
__global__ __launch_bounds__(256) void ln2_kernel(const float* __restrict__ g2,
                                                  const float* __restrict__ be2) {
    int n = blockIdx.x, t = threadIdx.x;
    const int2* row = (const int2*)(g_h2 + (size_t)n * GNN_DIM);
    int2 w = row[t];
    float v[4] = { bflo(w.x), bfhi(w.x), bflo(w.y), bfhi(w.y) };
    float sum = v[0] + v[1] + v[2] + v[3];
    float sq  = v[0]*v[0] + v[1]*v[1] + v[2]*v[2] + v[3]*v[3];
    #pragma unroll
    for (int off = 32; off; off >>= 1) { sum += __shfl_xor(sum, off); sq += __shfl_xor(sq, off); }
    __shared__ float s1[4], s2[4];
    if ((t & 63) == 0) { s1[t >> 6] = sum; s2[t >> 6] = sq; }
    __syncthreads();
    sum = s1[0] + s1[1] + s1[2] + s1[3];
    sq  = s2[0] + s2[1] + s2[2] + s2[3];
    float mu = sum * (1.f / GNN_DIM);
    float var = sq * (1.f / GNN_DIM) - mu * mu;
    float rstd = rsqrtf(var + 1e-5f);
    unsigned short* out = g_agg2 + (size_t)n * GNN_DIM + 4 * t;   // reuse agg2 as hln
    #pragma unroll
    for (int j = 0; j < 4; ++j) {
        int d = 4 * t + j;
        float y = (v[j] - mu) * rstd * g2[d] + be2[d];
        out[j] = f2bf(fmaxf(y, 0.f));
    }
}

// ---------------------------------------------------------------------------
// Pool: per-graph mean of [hln | fourier(coords)] -> gpool [64][2048]
// ---------------------------------------------------------------------------
__global__ __launch_bounds__(256) void pool_kernel(const float* __restrict__ coords,
                                                   const float* __restrict__ Bmat) {
    int g = blockIdx.x >> 3, chunk = blockIdx.x & 7;
    int d = chunk * 256 + threadIdx.x;
    int beg = g_goff[g], end = g_goff[g + 1];
    float sum = 0.f;
    if (d < GNN_DIM) {
        for (int n = beg; n < end; ++n)
            sum += __uint_as_float(((unsigned)g_agg2[(size_t)n * GNN_DIM + d]) << 16);
    } else {
        int f = d - GNN_DIM;
        int si = f >> 8, trig = (f >> 7) & 1, c = f & 127;
        const float SC[4] = {1.f, 5.f, 10.f, 30.f};
        float s = SC[si];
        float b0 = Bmat[c] * s, b1 = Bmat[128 + c] * s, b2 = Bmat[256 + c] * s;
        for (int n = beg; n < end; ++n) {
            float p = coords[n * 3] * b0 + coords[n * 3 + 1] * b1 + coords[n * 3 + 2] * b2;
            sum += trig ? __cosf(p) : __sinf(p);
        }
    }
    g_gpool[g * CAT_DIM + d] = sum / (float)max(end - beg, 1);
}

// ---------------------------------------------------------------------------
// Final: out = LN(gpool @ Wfc + bfc)   (64 blocks x 256 threads)
// ---------------------------------------------------------------------------
__global__ __launch_bounds__(256) void final_kernel(
        const float* __restrict__ Wfc, const float* __restrict__ bfc,
        const float* __restrict__ gfc, const float* __restrict__ befc,
        float* __restrict__ out) {
    int g = blockIdx.x, t = threadIdx.x;
    __shared__ float hg[CAT_DIM];
    for (int i = t; i < CAT_DIM; i += 256) hg[i] = g_gpool[g * CAT_DIM + i];
    __syncthreads();
    float acc = bfc[t];
    for (int k = 0; k < CAT_DIM; ++k) acc = fmaf(hg[k], Wfc[(size_t)k * OUT_DIM + t], acc);
    float sum = acc, sq = acc * acc;
    #pragma unroll
    for (int off = 32; off; off >>= 1) { sum += __shfl_xor(sum, off); sq += __shfl_xor(sq, off); }
    __shared__ float s1[4], s2[4];
    if ((t & 63) == 0) { s1[t >> 6] = sum; s2[t >> 6] = sq; }
    __syncthreads();
    sum = s1[0] + s1[1] + s1[2] + s1[3];
    sq  = s2[0] + s2[1] + s2[2] + s2[3];
    float mu = sum * (1.f / OUT_DIM);
    float var = sq * (1.f / OUT_DIM) - mu * mu;
    float rstd = rsqrtf(var + 1e-5f);
    out[g * OUT_DIM + t] = (acc - mu) * rstd * gfc[t] + befc[t];
}

// ---------------------------------------------------------------------------
extern "C" void kernel_launch(void* const* d_in, const int* in_sizes, int n_in,
                              void* d_out, int out_size, void* d_ws, size_t ws_size,
                              hipStream_t stream) {
    const float* x      = (const float*)d_in[0];
    const int*   ei     = (const int*)d_in[1];
    const float* coords = (const float*)d_in[2];
    const int*   batch  = (const int*)d_in[3];
    const float* Bmat   = (const float*)d_in[4];
    const float* W1l    = (const float*)d_in[5];
    const float* b1     = (const float*)d_in[6];
    const float* W1r    = (const float*)d_in[7];
    const float* g1     = (const float*)d_in[8];
    const float* be1    = (const float*)d_in[9];
    const float* W2l    = (const float*)d_in[10];
    const float* b2     = (const float*)d_in[11];
    const float* W2r    = (const float*)d_in[12];
    const float* g2     = (const float*)d_in[13];
    const float* be2    = (const float*)d_in[14];
    const float* Wfc    = (const float*)d_in[15];
    const float* bfc    = (const float*)d_in[16];
    const float* gfc    = (const float*)d_in[17];
    const float* befc   = (const float*)d_in[18];
    const int* src = ei;
    const int* dst = ei + N_EDGES;
    float* out = (float*)d_out;
    (void)in_sizes; (void)n_in; (void)out_size; (void)d_ws; (void)ws_size;

    unsigned short* w2lt;  hipGetSymbolAddress((void**)&w2lt, HIP_SYMBOL(g_w2lt));
    unsigned short* w2rt;  hipGetSymbolAddress((void**)&w2rt, HIP_SYMBOL(g_w2rt));

    zero_kernel<<<(N_NODES + 256) / 256, 256, 0, stream>>>();
    count_kernel<<<(N_EDGES + 255) / 256, 256, 0, stream>>>(dst, batch);
    scan_kernel<<<1, 1024, 0, stream>>>();
    goff_kernel<<<1, 64, 0, stream>>>();
    scatter_kernel<<<(N_EDGES + 255) / 256, 256, 0, stream>>>(src, dst);

    transpose_bf16<<<1024, 256, 0, stream>>>(W2l, w2lt);
    transpose_bf16<<<1024, 256, 0, stream>>>(W2r, w2rt);

    l1_agg_kernel<<<(N_NODES * 8 + 255) / 256, 256, 0, stream>>>(x);
    l1_transform_kernel<<<N_NODES, 256, 0, stream>>>(x, W1l, b1, W1r, g1, be1);

    l2_agg_kernel<<<N_NODES, 256, 0, stream>>>();

    gemm2_kernel<<<(M_PAD / BM) * (GNN_DIM / BN), 256, 0, stream>>>(b2);

    ln2_kernel<<<N_NODES, 256, 0, stream>>>(g2, be2);

    pool_kernel<<<N_GRAPHS * 8, 256, 0, stream>>>(coords, Bmat);

    final_kernel<<<N_GRAPHS, 256, 0, stream>>>(Wfc, bfc, gfc, befc, out);
}

// Round 3
// 1243.592 us; speedup vs baseline: 1.1061x; 1.1061x over previous
//
#include <hip/hip_runtime.h>
#include <hip/hip_bf16.h>

// ---------------------------------------------------------------------------
// GraphEncoder: SAGE(6->1024) -> LN -> ReLU -> SAGE(1024->1024) -> LN -> ReLU
//   -> concat(Fourier feats) -> per-graph mean pool -> FC(2048->256) -> LN
// ---------------------------------------------------------------------------

#define N_NODES 50000
#define N_EDGES 500000
#define N_GRAPHS 64
#define IN_DIM 6
#define GNN_DIM 1024
#define OUT_DIM 256
#define CAT_DIM 2048
#define M_PAD 50176   // 392 * 128  (392 = 8 XCDs * 49 row-groups)

typedef __attribute__((ext_vector_type(8))) short short8;
typedef __attribute__((ext_vector_type(4))) float f32x4;

// ---------------- static device scratch (allocated at module load) ---------
__device__ int g_cnt[N_NODES + 1];
__device__ int g_cursor[N_NODES];
__device__ int g_gcnt[N_GRAPHS];
__device__ int g_rowptr[N_NODES + 1];
__device__ int g_goff[N_GRAPHS + 1];
__device__ int g_esrc[N_EDGES];
__device__ unsigned short g_w2lt[(size_t)GNN_DIM * GNN_DIM];
__device__ unsigned short g_w2rt[(size_t)GNN_DIM * GNN_DIM];
__device__ float g_agg1[(size_t)N_NODES * IN_DIM];
__device__ unsigned short g_h[(size_t)M_PAD * GNN_DIM];
__device__ unsigned short g_agg2[(size_t)M_PAD * GNN_DIM];
__device__ unsigned short g_h2[(size_t)M_PAD * GNN_DIM];
__device__ float g_gpool[(size_t)N_GRAPHS * CAT_DIM];

__device__ __forceinline__ float bflo(int u) { return __uint_as_float(((unsigned)u) << 16); }
__device__ __forceinline__ float bfhi(int u) { return __uint_as_float(((unsigned)u) & 0xffff0000u); }
__device__ __forceinline__ unsigned short f2bf(float f) {
    unsigned u = __float_as_uint(f);
    unsigned rounded = u + 0x7fff + ((u >> 16) & 1);   // RNE
    return (unsigned short)(rounded >> 16);
}

// ---------------------------------------------------------------------------
// CSR build
// ---------------------------------------------------------------------------
__global__ void zero_kernel() {
    int i = blockIdx.x * 256 + threadIdx.x;
    if (i <= N_NODES) g_cnt[i] = 0;
    if (i < N_NODES) g_cursor[i] = 0;
    if (i < N_GRAPHS) g_gcnt[i] = 0;
}

__global__ void count_kernel(const int* __restrict__ dst, const int* __restrict__ batch) {
    int i = blockIdx.x * 256 + threadIdx.x;
    if (i < N_EDGES) atomicAdd(&g_cnt[dst[i]], 1);
    if (i < N_NODES) atomicAdd(&g_gcnt[batch[i]], 1);
}

// two-level scan: thread-serial chunk sums + wave shfl scan + cross-wave
__global__ __launch_bounds__(1024) void scan_kernel() {
    const int CH = 49;           // 1024 * 49 = 50176 >= N_NODES+1
    int t = threadIdx.x;
    int base = t * CH;
    int s = 0;
    #pragma unroll
    for (int i = 0; i < CH; ++i) {
        int n = base + i;
        s += (n < N_NODES) ? g_cnt[n] : 0;
    }
    int lane = t & 63, w = t >> 6;
    int x = s;
    #pragma unroll
    for (int off = 1; off < 64; off <<= 1) {
        int y = __shfl_up(x, off);
        if (lane >= off) x += y;
    }
    __shared__ int wsum[16], woff[16];
    if (lane == 63) wsum[w] = x;
    __syncthreads();
    if (t == 0) { int a = 0; for (int i = 0; i < 16; ++i) { woff[i] = a; a += wsum[i]; } }
    __syncthreads();
    int excl = x - s + woff[w];      // exclusive prefix at chunk start
    #pragma unroll
    for (int i = 0; i < CH; ++i) {
        int n = base + i;
        if (n <= N_NODES) g_rowptr[n] = excl;
        if (n < N_NODES) excl += g_cnt[n];
    }
}

__global__ void goff_kernel() {
    if (threadIdx.x == 0 && blockIdx.x == 0) {
        int acc = 0;
        for (int g = 0; g < N_GRAPHS; ++g) { g_goff[g] = acc; acc += g_gcnt[g]; }
        g_goff[N_GRAPHS] = acc;
    }
}

__global__ void scatter_kernel(const int* __restrict__ src, const int* __restrict__ dst) {
    int e = blockIdx.x * 256 + threadIdx.x;
    if (e >= N_EDGES) return;
    int d = dst[e];
    int pos = atomicAdd(&g_cursor[d], 1);
    g_esrc[g_rowptr[d] + pos] = src[e];
}

// ---------------------------------------------------------------------------
// Weight transpose f32 [K][N] -> bf16 [N][K]
// ---------------------------------------------------------------------------
__global__ void transpose_bf16(const float* __restrict__ W, unsigned short* __restrict__ Wt) {
    __shared__ float tile[32][33];
    int bx = blockIdx.x & 31, by = blockIdx.x >> 5;
    int tx = threadIdx.x & 31, ty = threadIdx.x >> 5;  // 32x8
    for (int i = 0; i < 32; i += 8)
        tile[ty + i][tx] = W[(size_t)(by * 32 + ty + i) * GNN_DIM + bx * 32 + tx];
    __syncthreads();
    for (int i = 0; i < 32; i += 8)
        Wt[(size_t)(bx * 32 + ty + i) * GNN_DIM + by * 32 + tx] = f2bf(tile[tx][ty + i]);
}

// ---------------------------------------------------------------------------
// Layer 1: mean-agg of x (6-dim), transform, LN, ReLU -> h (bf16)
// ---------------------------------------------------------------------------
__global__ void l1_agg_kernel(const float* __restrict__ x) {
    int id = blockIdx.x * 256 + threadIdx.x;
    int n = id >> 3, slot = id & 7;
    if (n >= N_NODES || slot >= IN_DIM) return;
    int beg = g_rowptr[n], end = g_rowptr[n + 1];
    float s = 0.f;
    for (int i = beg; i < end; ++i) s += x[(size_t)g_esrc[i] * IN_DIM + slot];
    g_agg1[n * IN_DIM + slot] = s / (float)max(end - beg, 1);
}

__global__ __launch_bounds__(256) void l1_transform_kernel(
        const float* __restrict__ x,
        const float* __restrict__ W1l, const float* __restrict__ b1,
        const float* __restrict__ W1r, const float* __restrict__ g1,
        const float* __restrict__ be1) {
    int n = blockIdx.x, t = threadIdx.x;
    __shared__ float xa[IN_DIM], aa[IN_DIM];
    if (t < IN_DIM) { xa[t] = x[n * IN_DIM + t]; aa[t] = g_agg1[n * IN_DIM + t]; }
    __syncthreads();
    float v[4];
    #pragma unroll
    for (int j = 0; j < 4; ++j) {
        int d = t + j * 256;
        float s = b1[d];
        #pragma unroll
        for (int k = 0; k < IN_DIM; ++k)
            s += aa[k] * W1l[k * GNN_DIM + d] + xa[k] * W1r[k * GNN_DIM + d];
        v[j] = s;
    }
    float sum = v[0] + v[1] + v[2] + v[3];
    float sq  = v[0]*v[0] + v[1]*v[1] + v[2]*v[2] + v[3]*v[3];
    #pragma unroll
    for (int off = 32; off; off >>= 1) { sum += __shfl_xor(sum, off); sq += __shfl_xor(sq, off); }
    __shared__ float s1[4], s2[4];
    if ((t & 63) == 0) { s1[t >> 6] = sum; s2[t >> 6] = sq; }
    __syncthreads();
    sum = s1[0] + s1[1] + s1[2] + s1[3];
    sq  = s2[0] + s2[1] + s2[2] + s2[3];
    float mu = sum * (1.f / GNN_DIM);
    float var = sq * (1.f / GNN_DIM) - mu * mu;
    float rstd = rsqrtf(var + 1e-5f);
    #pragma unroll
    for (int j = 0; j < 4; ++j) {
        int d = t + j * 256;
        float y = (v[j] - mu) * rstd * g1[d] + be1[d];
        y = fmaxf(y, 0.f);
        g_h[(size_t)n * GNN_DIM + d] = f2bf(y);
    }
}

// ---------------------------------------------------------------------------
// Layer 2 aggregation: agg2[n] = mean of h[src] over incident edges
// ---------------------------------------------------------------------------
__global__ __launch_bounds__(256) void l2_agg_kernel() {
    int n = blockIdx.x, t = threadIdx.x;
    int beg = g_rowptr[n], end = g_rowptr[n + 1];
    float s0 = 0.f, s1 = 0.f, s2 = 0.f, s3 = 0.f;
    __shared__ int el[256];
    for (int base = beg; base < end; base += 256) {
        int m = min(256, end - base);
        if (t < m) el[t] = g_esrc[base + t];
        __syncthreads();
        for (int i = 0; i < m; ++i) {
            const int2* hr = (const int2*)(g_h + (size_t)el[i] * GNN_DIM);
            int2 w = hr[t];   // 4 bf16: dims 4t..4t+3
            s0 += bflo(w.x); s1 += bfhi(w.x); s2 += bflo(w.y); s3 += bfhi(w.y);
        }
        __syncthreads();
    }
    float inv = 1.f / (float)max(end - beg, 1);
    unsigned short* out = g_agg2 + (size_t)n * GNN_DIM + 4 * t;
    out[0] = f2bf(s0 * inv); out[1] = f2bf(s1 * inv);
    out[2] = f2bf(s2 * inv); out[3] = f2bf(s3 * inv);
}

// ---------------------------------------------------------------------------
// Layer 2 GEMM: h2 = agg2 @ W2_l + h @ W2_r + b2  (bf16 MFMA)
// XCD-bijective tile remap (A-panel L2 locality) + st-style XOR swizzle
// (linear LDS dest + inverse-swizzled global source + swizzled ds_read).
// ---------------------------------------------------------------------------
#define BM 128
#define BN 128
#define BK 64

__global__ __launch_bounds__(256) void gemm2_kernel(const float* __restrict__ bias) {
    __shared__ __attribute__((aligned(16))) unsigned short As[BM * BK];
    __shared__ __attribute__((aligned(16))) unsigned short Bs[BN * BK];
    // grid = 392*8 = 3136. XCD = blockIdx%8 (round-robin). Give each XCD 49
    // contiguous bm-groups; all 8 bn of a bm are consecutive on one XCD.
    int i = blockIdx.x;
    int xcd = i & 7;
    int j = i >> 3;                 // 0..391
    int bm = xcd * 49 + (j >> 3);   // 0..391
    int bn = j & 7;
    int row0 = bm * BM, col0 = bn * BN;
    int t = threadIdx.x;
    int lane = t & 63, wid = t >> 6;
    int wr = wid >> 1, wc = wid & 1;     // 2x2 waves, each owns 64x64
    f32x4 acc[4][4] = {};
    // stage indexing: c = t + i*256, r = c>>3 (row), kb = (c&7)*16 (byte in row)
    int c0 = t;
    for (int seg = 0; seg < 2; ++seg) {
        const unsigned short* A  = seg ? g_h : g_agg2;
        const unsigned short* Bt = seg ? g_w2rt : g_w2lt;
        for (int k0 = 0; k0 < GNN_DIM; k0 += BK) {
            __syncthreads();
            #pragma unroll
            for (int u = 0; u < 4; ++u) {
                int c = c0 + u * 256;
                int r = c >> 3;
                int kb = (c & 7) * 16;                  // byte offset within row
                int kbs = kb ^ ((r & 7) << 4);          // inverse-swizzled source
                __builtin_amdgcn_global_load_lds(
                    (const __attribute__((address_space(1))) void*)(A + (size_t)(row0 + r) * GNN_DIM + k0 + (kbs >> 1)),
                    (__attribute__((address_space(3))) void*)(As + c * 8), 16, 0, 0);
            }
            #pragma unroll
            for (int u = 0; u < 4; ++u) {
                int c = c0 + u * 256;
                int r = c >> 3;
                int kb = (c & 7) * 16;
                int kbs = kb ^ ((r & 7) << 4);
                __builtin_amdgcn_global_load_lds(
                    (const __attribute__((address_space(1))) void*)(Bt + (size_t)(col0 + r) * GNN_DIM + k0 + (kbs >> 1)),
                    (__attribute__((address_space(3))) void*)(Bs + c * 8), 16, 0, 0);
            }
            asm volatile("s_waitcnt vmcnt(0)" ::: "memory");
            __syncthreads();
            #pragma unroll
            for (int kk = 0; kk < BK; kk += 32) {
                short8 a[4], b[4];
                int krd = kk + (lane >> 4) * 8;          // short index in row
                #pragma unroll
                for (int m = 0; m < 4; ++m) {
                    int row = wr * 64 + m * 16 + (lane & 15);
                    int ks = ((krd * 2) ^ ((row & 7) << 4)) >> 1;   // swizzled read
                    a[m] = *(const short8*)&As[row * BK + ks];
                }
                #pragma unroll
                for (int n = 0; n < 4; ++n) {
                    int row = wc * 64 + n * 16 + (lane & 15);
                    int ks = ((krd * 2) ^ ((row & 7) << 4)) >> 1;
                    b[n] = *(const short8*)&Bs[row * BK + ks];
                }
                #pragma unroll
                for (int m = 0; m < 4; ++m)
                    #pragma unroll
                    for (int n = 0; n < 4; ++n)
                        acc[m][n] = __builtin_amdgcn_mfma_f32_16x16x32_bf16(a[m], b[n], acc[m][n], 0, 0, 0);
            }
        }
    }
    #pragma unroll
    for (int m = 0; m < 4; ++m) {
        #pragma unroll
        for (int n = 0; n < 4; ++n) {
            int col = col0 + wc * 64 + n * 16 + (lane & 15);
            int rbase = row0 + wr * 64 + m * 16 + (lane >> 4) * 4;
            float bv = bias[col];
            #pragma unroll
            for (int r = 0; r < 4; ++r) {
                float v = acc[m][n][r] + bv;
                g_h2[(size_t)(rbase + r) * GNN_DIM + col] = f2bf(v);
            }
        }
    }
}

// ---------------------------------------------------------------------------
// Layer 2 LN + ReLU: hln = relu(LN(h2)*g2+be2)  (written back over g_agg2)
// ---------------------------------------------------------------------------
__global__ __launch_bounds__(256) void ln2_kernel(const float* __restrict__ g2,
                                                  const float* __restrict__ be2) {
    int n = blockIdx.x, t = threadIdx.x;
    const int2* row = (const int2*)(g_h2 + (size_t)n * GNN_DIM);
    int2 w = row[t];
    float v[4] = { bflo(w.x), bfhi(w.x), bflo(w.y), bfhi(w.y) };
    float sum = v[0] + v[1] + v[2] + v[3];
    float sq  = v[0]*v[0] + v[1]*v[1] + v[2]*v[2] + v[3]*v[3];
    #pragma unroll
    for (int off = 32; off; off >>= 1) { sum += __shfl_xor(sum, off); sq += __shfl_xor(sq, off); }
    __shared__ float s1[4], s2[4];
    if ((t & 63) == 0) { s1[t >> 6] = sum; s2[t >> 6] = sq; }
    __syncthreads();
    sum = s1[0] + s1[1] + s1[2] + s1[3];
    sq  = s2[0] + s2[1] + s2[2] + s2[3];
    float mu = sum * (1.f / GNN_DIM);
    float var = sq * (1.f / GNN_DIM) - mu * mu;
    float rstd = rsqrtf(var + 1e-5f);
    unsigned short* out = g_agg2 + (size_t)n * GNN_DIM + 4 * t;   // reuse agg2 as hln
    #pragma unroll
    for (int j = 0; j < 4; ++j) {
        int d = 4 * t + j;
        float y = (v[j] - mu) * rstd * g2[d] + be2[d];
        out[j] = f2bf(fmaxf(y, 0.f));
    }
}

// ---------------------------------------------------------------------------
// Pool: per-graph mean of [hln | fourier(coords)] -> gpool [64][2048]
// ---------------------------------------------------------------------------
__global__ __launch_bounds__(256) void pool_kernel(const float* __restrict__ coords,
                                                   const float* __restrict__ Bmat) {
    int g = blockIdx.x >> 3, chunk = blockIdx.x & 7;
    int d = chunk * 256 + threadIdx.x;
    int beg = g_goff[g], end = g_goff[g + 1];
    float sum = 0.f;
    if (d < GNN_DIM) {
        for (int n = beg; n < end; ++n)
            sum += __uint_as_float(((unsigned)g_agg2[(size_t)n * GNN_DIM + d]) << 16);
    } else {
        int f = d - GNN_DIM;
        int si = f >> 8, trig = (f >> 7) & 1, c = f & 127;
        const float SC[4] = {1.f, 5.f, 10.f, 30.f};
        float s = SC[si];
        float b0 = Bmat[c] * s, b1 = Bmat[128 + c] * s, b2 = Bmat[256 + c] * s;
        for (int n = beg; n < end; ++n) {
            float p = coords[n * 3] * b0 + coords[n * 3 + 1] * b1 + coords[n * 3 + 2] * b2;
            sum += trig ? __cosf(p) : __sinf(p);
        }
    }
    g_gpool[g * CAT_DIM + d] = sum / (float)max(end - beg, 1);
}

// ---------------------------------------------------------------------------
// Final: out = LN(gpool @ Wfc + bfc)   (64 blocks x 256 threads)
// ---------------------------------------------------------------------------
__global__ __launch_bounds__(256) void final_kernel(
        const float* __restrict__ Wfc, const float* __restrict__ bfc,
        const float* __restrict__ gfc, const float* __restrict__ befc,
        float* __restrict__ out) {
    int g = blockIdx.x, t = threadIdx.x;
    __shared__ float hg[CAT_DIM];
    for (int i = t; i < CAT_DIM; i += 256) hg[i] = g_gpool[g * CAT_DIM + i];
    __syncthreads();
    float acc = bfc[t];
    for (int k = 0; k < CAT_DIM; ++k) acc = fmaf(hg[k], Wfc[(size_t)k * OUT_DIM + t], acc);
    float sum = acc, sq = acc * acc;
    #pragma unroll
    for (int off = 32; off; off >>= 1) { sum += __shfl_xor(sum, off); sq += __shfl_xor(sq, off); }
    __shared__ float s1[4], s2[4];
    if ((t & 63) == 0) { s1[t >> 6] = sum; s2[t >> 6] = sq; }
    __syncthreads();
    sum = s1[0] + s1[1] + s1[2] + s1[3];
    sq  = s2[0] + s2[1] + s2[2] + s2[3];
    float mu = sum * (1.f / OUT_DIM);
    float var = sq * (1.f / OUT_DIM) - mu * mu;
    float rstd = rsqrtf(var + 1e-5f);
    out[g * OUT_DIM + t] = (acc - mu) * rstd * gfc[t] + befc[t];
}

// ---------------------------------------------------------------------------
extern "C" void kernel_launch(void* const* d_in, const int* in_sizes, int n_in,
                              void* d_out, int out_size, void* d_ws, size_t ws_size,
                              hipStream_t stream) {
    const float* x      = (const float*)d_in[0];
    const int*   ei     = (const int*)d_in[1];
    const float* coords = (const float*)d_in[2];
    const int*   batch  = (const int*)d_in[3];
    const float* Bmat   = (const float*)d_in[4];
    const float* W1l    = (const float*)d_in[5];
    const float* b1     = (const float*)d_in[6];
    const float* W1r    = (const float*)d_in[7];
    const float* g1     = (const float*)d_in[8];
    const float* be1    = (const float*)d_in[9];
    const float* W2l    = (const float*)d_in[10];
    const float* b2     = (const float*)d_in[11];
    const float* W2r    = (const float*)d_in[12];
    const float* g2     = (const float*)d_in[13];
    const float* be2    = (const float*)d_in[14];
    const float* Wfc    = (const float*)d_in[15];
    const float* bfc    = (const float*)d_in[16];
    const float* gfc    = (const float*)d_in[17];
    const float* befc   = (const float*)d_in[18];
    const int* src = ei;
    const int* dst = ei + N_EDGES;
    float* out = (float*)d_out;
    (void)in_sizes; (void)n_in; (void)out_size; (void)d_ws; (void)ws_size;

    unsigned short* w2lt;  hipGetSymbolAddress((void**)&w2lt, HIP_SYMBOL(g_w2lt));
    unsigned short* w2rt;  hipGetSymbolAddress((void**)&w2rt, HIP_SYMBOL(g_w2rt));

    zero_kernel<<<(N_NODES + 256) / 256, 256, 0, stream>>>();
    count_kernel<<<(N_EDGES + 255) / 256, 256, 0, stream>>>(dst, batch);
    scan_kernel<<<1, 1024, 0, stream>>>();
    goff_kernel<<<1, 64, 0, stream>>>();
    scatter_kernel<<<(N_EDGES + 255) / 256, 256, 0, stream>>>(src, dst);

    transpose_bf16<<<1024, 256, 0, stream>>>(W2l, w2lt);
    transpose_bf16<<<1024, 256, 0, stream>>>(W2r, w2rt);

    l1_agg_kernel<<<(N_NODES * 8 + 255) / 256, 256, 0, stream>>>(x);
    l1_transform_kernel<<<N_NODES, 256, 0, stream>>>(x, W1l, b1, W1r, g1, be1);

    l2_agg_kernel<<<N_NODES, 256, 0, stream>>>();

    gemm2_kernel<<<(M_PAD / BM) * (GNN_DIM / BN), 256, 0, stream>>>(b2);

    ln2_kernel<<<N_NODES, 256, 0, stream>>>(g2, be2);

    pool_kernel<<<N_GRAPHS * 8, 256, 0, stream>>>(coords, Bmat);

    final_kernel<<<N_GRAPHS, 256, 0, stream>>>(Wfc, bfc, gfc, befc, out);
}

// Round 4
// 1072.549 us; speedup vs baseline: 1.2825x; 1.1595x over previous
//
#include <hip/hip_runtime.h>
#include <hip/hip_bf16.h>

// ---------------------------------------------------------------------------
// GraphEncoder: SAGE(6->1024) -> LN -> ReLU -> SAGE(1024->1024) -> LN -> ReLU
//   -> concat(Fourier feats) -> per-graph mean pool -> FC(2048->256) -> LN
// ---------------------------------------------------------------------------

#define N_NODES 50000
#define N_EDGES 500000
#define N_GRAPHS 64
#define IN_DIM 6
#define GNN_DIM 1024
#define OUT_DIM 256
#define CAT_DIM 2048
#define M_PAD 50176   // 392 * 128  (392 = 8 XCDs * 49 row-groups)

typedef __attribute__((ext_vector_type(8))) short short8;
typedef __attribute__((ext_vector_type(4))) float f32x4;

// ---------------- static device scratch (allocated at module load) ---------
__device__ int g_cnt[N_NODES + 1];
__device__ int g_cursor[N_NODES];
__device__ int g_gcnt[N_GRAPHS];
__device__ int g_rowptr[N_NODES + 1];
__device__ int g_goff[N_GRAPHS + 1];
__device__ int g_esrc[N_EDGES];
__device__ __attribute__((aligned(256))) unsigned short g_w2lt[(size_t)GNN_DIM * GNN_DIM];
__device__ __attribute__((aligned(256))) unsigned short g_w2rt[(size_t)GNN_DIM * GNN_DIM];
__device__ float g_agg1[(size_t)N_NODES * IN_DIM];
__device__ __attribute__((aligned(256))) unsigned short g_h[(size_t)M_PAD * GNN_DIM];
__device__ __attribute__((aligned(256))) unsigned short g_agg2[(size_t)M_PAD * GNN_DIM];
__device__ __attribute__((aligned(256))) unsigned short g_h2[(size_t)M_PAD * GNN_DIM];
__device__ float g_gpool[(size_t)N_GRAPHS * CAT_DIM];

__device__ __forceinline__ float bflo(int u) { return __uint_as_float(((unsigned)u) << 16); }
__device__ __forceinline__ float bfhi(int u) { return __uint_as_float(((unsigned)u) & 0xffff0000u); }
__device__ __forceinline__ unsigned short f2bf(float f) {
    unsigned u = __float_as_uint(f);
    unsigned rounded = u + 0x7fff + ((u >> 16) & 1);   // RNE
    return (unsigned short)(rounded >> 16);
}
__device__ __forceinline__ int pack2(unsigned short a, unsigned short b) {
    return (int)((unsigned)a | ((unsigned)b << 16));
}

// ---------------------------------------------------------------------------
// CSR build
// ---------------------------------------------------------------------------
__global__ void zero_kernel() {
    int i = blockIdx.x * 256 + threadIdx.x;
    if (i <= N_NODES) g_cnt[i] = 0;
    if (i < N_NODES) g_cursor[i] = 0;
    if (i < N_GRAPHS) g_gcnt[i] = 0;
}

__global__ void count_kernel(const int* __restrict__ dst, const int* __restrict__ batch) {
    int i = blockIdx.x * 256 + threadIdx.x;
    if (i < N_EDGES) atomicAdd(&g_cnt[dst[i]], 1);
    if (i < N_NODES) atomicAdd(&g_gcnt[batch[i]], 1);
}

// two-level scan: thread-serial chunk sums + wave shfl scan + cross-wave
__global__ __launch_bounds__(1024) void scan_kernel() {
    const int CH = 49;           // 1024 * 49 = 50176 >= N_NODES+1
    int t = threadIdx.x;
    int base = t * CH;
    int s = 0;
    #pragma unroll
    for (int i = 0; i < CH; ++i) {
        int n = base + i;
        s += (n < N_NODES) ? g_cnt[n] : 0;
    }
    int lane = t & 63, w = t >> 6;
    int x = s;
    #pragma unroll
    for (int off = 1; off < 64; off <<= 1) {
        int y = __shfl_up(x, off);
        if (lane >= off) x += y;
    }
    __shared__ int wsum[16], woff[16];
    if (lane == 63) wsum[w] = x;
    __syncthreads();
    if (t == 0) { int a = 0; for (int i = 0; i < 16; ++i) { woff[i] = a; a += wsum[i]; } }
    __syncthreads();
    int excl = x - s + woff[w];      // exclusive prefix at chunk start
    #pragma unroll
    for (int i = 0; i < CH; ++i) {
        int n = base + i;
        if (n <= N_NODES) g_rowptr[n] = excl;
        if (n < N_NODES) excl += g_cnt[n];
    }
}

__global__ void goff_kernel() {
    if (threadIdx.x == 0 && blockIdx.x == 0) {
        int acc = 0;
        for (int g = 0; g < N_GRAPHS; ++g) { g_goff[g] = acc; acc += g_gcnt[g]; }
        g_goff[N_GRAPHS] = acc;
    }
}

__global__ void scatter_kernel(const int* __restrict__ src, const int* __restrict__ dst) {
    int e = blockIdx.x * 256 + threadIdx.x;
    if (e >= N_EDGES) return;
    int d = dst[e];
    int pos = atomicAdd(&g_cursor[d], 1);
    g_esrc[g_rowptr[d] + pos] = src[e];
}

// ---------------------------------------------------------------------------
// Weight transpose f32 [K][N] -> bf16 [N][K]
// ---------------------------------------------------------------------------
__global__ void transpose_bf16(const float* __restrict__ W, unsigned short* __restrict__ Wt) {
    __shared__ float tile[32][33];
    int bx = blockIdx.x & 31, by = blockIdx.x >> 5;
    int tx = threadIdx.x & 31, ty = threadIdx.x >> 5;  // 32x8
    for (int i = 0; i < 32; i += 8)
        tile[ty + i][tx] = W[(size_t)(by * 32 + ty + i) * GNN_DIM + bx * 32 + tx];
    __syncthreads();
    for (int i = 0; i < 32; i += 8)
        Wt[(size_t)(bx * 32 + ty + i) * GNN_DIM + by * 32 + tx] = f2bf(tile[tx][ty + i]);
}

// ---------------------------------------------------------------------------
// Layer 1: mean-agg of x (6-dim), transform, LN, ReLU -> h (bf16)
// ---------------------------------------------------------------------------
__global__ void l1_agg_kernel(const float* __restrict__ x) {
    int id = blockIdx.x * 256 + threadIdx.x;
    int n = id >> 3, slot = id & 7;
    if (n >= N_NODES || slot >= IN_DIM) return;
    int beg = g_rowptr[n], end = g_rowptr[n + 1];
    float s = 0.f;
    for (int i = beg; i < end; ++i) s += x[(size_t)g_esrc[i] * IN_DIM + slot];
    g_agg1[n * IN_DIM + slot] = s / (float)max(end - beg, 1);
}

// 8 nodes per block; weights held in registers (dims t*4..t*4+3 per thread)
__global__ __launch_bounds__(256) void l1_transform_kernel(
        const float* __restrict__ x,
        const float* __restrict__ W1l, const float* __restrict__ b1,
        const float* __restrict__ W1r, const float* __restrict__ g1,
        const float* __restrict__ be1) {
    int t = threadIdx.x;
    int nb = blockIdx.x * 8;                 // 6250 blocks * 8 = 50000 exact
    float4 wl[6], wr[6];
    #pragma unroll
    for (int k = 0; k < 6; ++k) {
        wl[k] = *(const float4*)&W1l[k * GNN_DIM + t * 4];
        wr[k] = *(const float4*)&W1r[k * GNN_DIM + t * 4];
    }
    float4 bb = *(const float4*)&b1[t * 4];
    float4 gg = *(const float4*)&g1[t * 4];
    float4 be = *(const float4*)&be1[t * 4];
    __shared__ float sx[48], sa[48];
    if (t < 48) sx[t] = x[nb * 6 + t];
    else if (t < 96) sa[t - 48] = g_agg1[nb * 6 + (t - 48)];
    __syncthreads();
    __shared__ float s1[4], s2[4];
    for (int u = 0; u < 8; ++u) {
        int n = nb + u;
        float4 v = bb;
        #pragma unroll
        for (int k = 0; k < 6; ++k) {
            float a = sa[u * 6 + k], xx = sx[u * 6 + k];
            v.x += a * wl[k].x + xx * wr[k].x;
            v.y += a * wl[k].y + xx * wr[k].y;
            v.z += a * wl[k].z + xx * wr[k].z;
            v.w += a * wl[k].w + xx * wr[k].w;
        }
        float sum = v.x + v.y + v.z + v.w;
        float sq  = v.x*v.x + v.y*v.y + v.z*v.z + v.w*v.w;
        #pragma unroll
        for (int off = 32; off; off >>= 1) { sum += __shfl_xor(sum, off); sq += __shfl_xor(sq, off); }
        if ((t & 63) == 0) { s1[t >> 6] = sum; s2[t >> 6] = sq; }
        __syncthreads();
        sum = s1[0] + s1[1] + s1[2] + s1[3];
        sq  = s2[0] + s2[1] + s2[2] + s2[3];
        __syncthreads();
        float mu = sum * (1.f / GNN_DIM);
        float var = sq * (1.f / GNN_DIM) - mu * mu;
        float rstd = rsqrtf(var + 1e-5f);
        float y0 = fmaxf((v.x - mu) * rstd * gg.x + be.x, 0.f);
        float y1 = fmaxf((v.y - mu) * rstd * gg.y + be.y, 0.f);
        float y2 = fmaxf((v.z - mu) * rstd * gg.z + be.z, 0.f);
        float y3 = fmaxf((v.w - mu) * rstd * gg.w + be.w, 0.f);
        int2 pk;
        pk.x = pack2(f2bf(y0), f2bf(y1));
        pk.y = pack2(f2bf(y2), f2bf(y3));
        *(int2*)(g_h + (size_t)n * GNN_DIM + t * 4) = pk;
    }
}

// ---------------------------------------------------------------------------
// Layer 2 aggregation: agg2[n] = mean of h[src] rows. Wave-per-node,
// int4 (16B) loads, 4-edge unroll for MLP.
// ---------------------------------------------------------------------------
#define ACC8(v, base) do { \
    s[base+0] += bflo((v).x); s[base+1] += bfhi((v).x); \
    s[base+2] += bflo((v).y); s[base+3] += bfhi((v).y); \
    s[base+4] += bflo((v).z); s[base+5] += bfhi((v).z); \
    s[base+6] += bflo((v).w); s[base+7] += bfhi((v).w); \
} while (0)

__global__ __launch_bounds__(256) void l2_agg_kernel() {
    int wave = threadIdx.x >> 6, lane = threadIdx.x & 63;
    int n = blockIdx.x * 4 + wave;           // 12500 * 4 = 50000 exact
    int beg = g_rowptr[n], end = g_rowptr[n + 1];
    float s[16];
    #pragma unroll
    for (int j = 0; j < 16; ++j) s[j] = 0.f;
    const int4* hp = (const int4*)g_h;       // row = 128 int4
    int i = beg;
    for (; i + 4 <= end; i += 4) {
        int e0 = g_esrc[i], e1 = g_esrc[i + 1], e2 = g_esrc[i + 2], e3 = g_esrc[i + 3];
        int4 a0 = hp[(size_t)e0 * 128 + lane],      a1 = hp[(size_t)e0 * 128 + 64 + lane];
        int4 b0 = hp[(size_t)e1 * 128 + lane],      b1 = hp[(size_t)e1 * 128 + 64 + lane];
        int4 c0 = hp[(size_t)e2 * 128 + lane],      c1 = hp[(size_t)e2 * 128 + 64 + lane];
        int4 d0 = hp[(size_t)e3 * 128 + lane],      d1 = hp[(size_t)e3 * 128 + 64 + lane];
        ACC8(a0, 0); ACC8(a1, 8);
        ACC8(b0, 0); ACC8(b1, 8);
        ACC8(c0, 0); ACC8(c1, 8);
        ACC8(d0, 0); ACC8(d1, 8);
    }
    for (; i < end; ++i) {
        int e0 = g_esrc[i];
        int4 a0 = hp[(size_t)e0 * 128 + lane], a1 = hp[(size_t)e0 * 128 + 64 + lane];
        ACC8(a0, 0); ACC8(a1, 8);
    }
    float inv = 1.f / (float)max(end - beg, 1);
    int4 w0, w1;
    w0.x = pack2(f2bf(s[0] * inv),  f2bf(s[1] * inv));
    w0.y = pack2(f2bf(s[2] * inv),  f2bf(s[3] * inv));
    w0.z = pack2(f2bf(s[4] * inv),  f2bf(s[5] * inv));
    w0.w = pack2(f2bf(s[6] * inv),  f2bf(s[7] * inv));
    w1.x = pack2(f2bf(s[8] * inv),  f2bf(s[9] * inv));
    w1.y = pack2(f2bf(s[10] * inv), f2bf(s[11] * inv));
    w1.z = pack2(f2bf(s[12] * inv), f2bf(s[13] * inv));
    w1.w = pack2(f2bf(s[14] * inv), f2bf(s[15] * inv));
    *(int4*)(g_agg2 + (size_t)n * GNN_DIM + lane * 8) = w0;
    *(int4*)(g_agg2 + (size_t)n * GNN_DIM + 512 + lane * 8) = w1;
}

// ---------------------------------------------------------------------------
// Layer 2 GEMM: h2 = agg2 @ W2_l + h @ W2_r + b2  (bf16 MFMA)
// XCD-bijective tile remap (A-panel L2 locality) + XOR swizzle
// (linear LDS dest + inverse-swizzled global source + swizzled ds_read).
// ---------------------------------------------------------------------------
#define BM 128
#define BN 128
#define BK 64

__global__ __launch_bounds__(256) void gemm2_kernel(const float* __restrict__ bias) {
    __shared__ __attribute__((aligned(16))) unsigned short As[BM * BK];
    __shared__ __attribute__((aligned(16))) unsigned short Bs[BN * BK];
    int i = blockIdx.x;
    int xcd = i & 7;
    int j = i >> 3;                 // 0..391
    int bm = xcd * 49 + (j >> 3);   // 0..391
    int bn = j & 7;
    int row0 = bm * BM, col0 = bn * BN;
    int t = threadIdx.x;
    int lane = t & 63, wid = t >> 6;
    int wr = wid >> 1, wc = wid & 1;     // 2x2 waves, each owns 64x64
    f32x4 acc[4][4] = {};
    int c0 = t;
    for (int seg = 0; seg < 2; ++seg) {
        const unsigned short* A  = seg ? g_h : g_agg2;
        const unsigned short* Bt = seg ? g_w2rt : g_w2lt;
        for (int k0 = 0; k0 < GNN_DIM; k0 += BK) {
            __syncthreads();
            #pragma unroll
            for (int u = 0; u < 4; ++u) {
                int c = c0 + u * 256;
                int r = c >> 3;
                int kb = (c & 7) * 16;                  // byte offset within row
                int kbs = kb ^ ((r & 7) << 4);          // inverse-swizzled source
                __builtin_amdgcn_global_load_lds(
                    (const __attribute__((address_space(1))) void*)(A + (size_t)(row0 + r) * GNN_DIM + k0 + (kbs >> 1)),
                    (__attribute__((address_space(3))) void*)(As + c * 8), 16, 0, 0);
            }
            #pragma unroll
            for (int u = 0; u < 4; ++u) {
                int c = c0 + u * 256;
                int r = c >> 3;
                int kb = (c & 7) * 16;
                int kbs = kb ^ ((r & 7) << 4);
                __builtin_amdgcn_global_load_lds(
                    (const __attribute__((address_space(1))) void*)(Bt + (size_t)(col0 + r) * GNN_DIM + k0 + (kbs >> 1)),
                    (__attribute__((address_space(3))) void*)(Bs + c * 8), 16, 0, 0);
            }
            asm volatile("s_waitcnt vmcnt(0)" ::: "memory");
            __syncthreads();
            #pragma unroll
            for (int kk = 0; kk < BK; kk += 32) {
                short8 a[4], b[4];
                int krd = kk + (lane >> 4) * 8;          // short index in row
                #pragma unroll
                for (int m = 0; m < 4; ++m) {
                    int row = wr * 64 + m * 16 + (lane & 15);
                    int ks = ((krd * 2) ^ ((row & 7) << 4)) >> 1;   // swizzled read
                    a[m] = *(const short8*)&As[row * BK + ks];
                }
                #pragma unroll
                for (int n = 0; n < 4; ++n) {
                    int row = wc * 64 + n * 16 + (lane & 15);
                    int ks = ((krd * 2) ^ ((row & 7) << 4)) >> 1;
                    b[n] = *(const short8*)&Bs[row * BK + ks];
                }
                #pragma unroll
                for (int m = 0; m < 4; ++m)
                    #pragma unroll
                    for (int n = 0; n < 4; ++n)
                        acc[m][n] = __builtin_amdgcn_mfma_f32_16x16x32_bf16(a[m], b[n], acc[m][n], 0, 0, 0);
            }
        }
    }
    #pragma unroll
    for (int m = 0; m < 4; ++m) {
        #pragma unroll
        for (int n = 0; n < 4; ++n) {
            int col = col0 + wc * 64 + n * 16 + (lane & 15);
            int rbase = row0 + wr * 64 + m * 16 + (lane >> 4) * 4;
            float bv = bias[col];
            #pragma unroll
            for (int r = 0; r < 4; ++r) {
                float v = acc[m][n][r] + bv;
                g_h2[(size_t)(rbase + r) * GNN_DIM + col] = f2bf(v);
            }
        }
    }
}

// ---------------------------------------------------------------------------
// Layer 2 LN + ReLU: hln = relu(LN(h2)*g2+be2)  (written back over g_agg2)
// ---------------------------------------------------------------------------
__global__ __launch_bounds__(256) void ln2_kernel(const float* __restrict__ g2,
                                                  const float* __restrict__ be2) {
    int n = blockIdx.x, t = threadIdx.x;
    const int2* row = (const int2*)(g_h2 + (size_t)n * GNN_DIM);
    int2 w = row[t];
    float v[4] = { bflo(w.x), bfhi(w.x), bflo(w.y), bfhi(w.y) };
    float sum = v[0] + v[1] + v[2] + v[3];
    float sq  = v[0]*v[0] + v[1]*v[1] + v[2]*v[2] + v[3]*v[3];
    #pragma unroll
    for (int off = 32; off; off >>= 1) { sum += __shfl_xor(sum, off); sq += __shfl_xor(sq, off); }
    __shared__ float s1[4], s2[4];
    if ((t & 63) == 0) { s1[t >> 6] = sum; s2[t >> 6] = sq; }
    __syncthreads();
    sum = s1[0] + s1[1] + s1[2] + s1[3];
    sq  = s2[0] + s2[1] + s2[2] + s2[3];
    float mu = sum * (1.f / GNN_DIM);
    float var = sq * (1.f / GNN_DIM) - mu * mu;
    float rstd = rsqrtf(var + 1e-5f);
    unsigned short* out = g_agg2 + (size_t)n * GNN_DIM + 4 * t;   // reuse agg2 as hln
    #pragma unroll
    for (int j = 0; j < 4; ++j) {
        int d = 4 * t + j;
        float y = (v[j] - mu) * rstd * g2[d] + be2[d];
        out[j] = f2bf(fmaxf(y, 0.f));
    }
}

// ---------------------------------------------------------------------------
// Pool: per-graph mean of [hln | fourier(coords)] -> gpool [64][2048]
// ---------------------------------------------------------------------------
__global__ __launch_bounds__(256) void pool_kernel(const float* __restrict__ coords,
                                                   const float* __restrict__ Bmat) {
    int g = blockIdx.x >> 3, chunk = blockIdx.x & 7;
    int d = chunk * 256 + threadIdx.x;
    int beg = g_goff[g], end = g_goff[g + 1];
    float sum = 0.f;
    if (d < GNN_DIM) {
        for (int n = beg; n < end; ++n)
            sum += __uint_as_float(((unsigned)g_agg2[(size_t)n * GNN_DIM + d]) << 16);
    } else {
        int f = d - GNN_DIM;
        int si = f >> 8, trig = (f >> 7) & 1, c = f & 127;
        const float SC[4] = {1.f, 5.f, 10.f, 30.f};
        float s = SC[si];
        float b0 = Bmat[c] * s, b1 = Bmat[128 + c] * s, b2 = Bmat[256 + c] * s;
        for (int n = beg; n < end; ++n) {
            float p = coords[n * 3] * b0 + coords[n * 3 + 1] * b1 + coords[n * 3 + 2] * b2;
            sum += trig ? __cosf(p) : __sinf(p);
        }
    }
    g_gpool[g * CAT_DIM + d] = sum / (float)max(end - beg, 1);
}

// ---------------------------------------------------------------------------
// Final: out = LN(gpool @ Wfc + bfc)   (64 blocks x 256 threads)
// ---------------------------------------------------------------------------
__global__ __launch_bounds__(256) void final_kernel(
        const float* __restrict__ Wfc, const float* __restrict__ bfc,
        const float* __restrict__ gfc, const float* __restrict__ befc,
        float* __restrict__ out) {
    int g = blockIdx.x, t = threadIdx.x;
    __shared__ float hg[CAT_DIM];
    for (int i = t; i < CAT_DIM; i += 256) hg[i] = g_gpool[g * CAT_DIM + i];
    __syncthreads();
    float acc = bfc[t];
    for (int k = 0; k < CAT_DIM; ++k) acc = fmaf(hg[k], Wfc[(size_t)k * OUT_DIM + t], acc);
    float sum = acc, sq = acc * acc;
    #pragma unroll
    for (int off = 32; off; off >>= 1) { sum += __shfl_xor(sum, off); sq += __shfl_xor(sq, off); }
    __shared__ float s1[4], s2[4];
    if ((t & 63) == 0) { s1[t >> 6] = sum; s2[t >> 6] = sq; }
    __syncthreads();
    sum = s1[0] + s1[1] + s1[2] + s1[3];
    sq  = s2[0] + s2[1] + s2[2] + s2[3];
    float mu = sum * (1.f / OUT_DIM);
    float var = sq * (1.f / OUT_DIM) - mu * mu;
    float rstd = rsqrtf(var + 1e-5f);
    out[g * OUT_DIM + t] = (acc - mu) * rstd * gfc[t] + befc[t];
}

// ---------------------------------------------------------------------------
extern "C" void kernel_launch(void* const* d_in, const int* in_sizes, int n_in,
                              void* d_out, int out_size, void* d_ws, size_t ws_size,
                              hipStream_t stream) {
    const float* x      = (const float*)d_in[0];
    const int*   ei     = (const int*)d_in[1];
    const float* coords = (const float*)d_in[2];
    const int*   batch  = (const int*)d_in[3];
    const float* Bmat   = (const float*)d_in[4];
    const float* W1l    = (const float*)d_in[5];
    const float* b1     = (const float*)d_in[6];
    const float* W1r    = (const float*)d_in[7];
    const float* g1     = (const float*)d_in[8];
    const float* be1    = (const float*)d_in[9];
    const float* W2l    = (const float*)d_in[10];
    const float* b2     = (const float*)d_in[11];
    const float* W2r    = (const float*)d_in[12];
    const float* g2     = (const float*)d_in[13];
    const float* be2    = (const float*)d_in[14];
    const float* Wfc    = (const float*)d_in[15];
    const float* bfc    = (const float*)d_in[16];
    const float* gfc    = (const float*)d_in[17];
    const float* befc   = (const float*)d_in[18];
    const int* src = ei;
    const int* dst = ei + N_EDGES;
    float* out = (float*)d_out;
    (void)in_sizes; (void)n_in; (void)out_size; (void)d_ws; (void)ws_size;

    unsigned short* w2lt;  hipGetSymbolAddress((void**)&w2lt, HIP_SYMBOL(g_w2lt));
    unsigned short* w2rt;  hipGetSymbolAddress((void**)&w2rt, HIP_SYMBOL(g_w2rt));

    zero_kernel<<<(N_NODES + 256) / 256, 256, 0, stream>>>();
    count_kernel<<<(N_EDGES + 255) / 256, 256, 0, stream>>>(dst, batch);
    scan_kernel<<<1, 1024, 0, stream>>>();
    goff_kernel<<<1, 64, 0, stream>>>();
    scatter_kernel<<<(N_EDGES + 255) / 256, 256, 0, stream>>>(src, dst);

    transpose_bf16<<<1024, 256, 0, stream>>>(W2l, w2lt);
    transpose_bf16<<<1024, 256, 0, stream>>>(W2r, w2rt);

    l1_agg_kernel<<<(N_NODES * 8 + 255) / 256, 256, 0, stream>>>(x);
    l1_transform_kernel<<<N_NODES / 8, 256, 0, stream>>>(x, W1l, b1, W1r, g1, be1);

    l2_agg_kernel<<<N_NODES / 4, 256, 0, stream>>>();

    gemm2_kernel<<<(M_PAD / BM) * (GNN_DIM / BN), 256, 0, stream>>>(b2);

    ln2_kernel<<<N_NODES, 256, 0, stream>>>(g2, be2);

    pool_kernel<<<N_GRAPHS * 8, 256, 0, stream>>>(coords, Bmat);

    final_kernel<<<N_GRAPHS, 256, 0, stream>>>(Wfc, bfc, gfc, befc, out);
}

// Round 5
// 907.045 us; speedup vs baseline: 1.5166x; 1.1825x over previous
//
#include <hip/hip_runtime.h>
#include <hip/hip_bf16.h>

// ---------------------------------------------------------------------------
// GraphEncoder: SAGE(6->1024) -> LN -> ReLU -> SAGE(1024->1024) -> LN -> ReLU
//   -> concat(Fourier feats) -> per-graph mean pool -> FC(2048->256) -> LN
// ---------------------------------------------------------------------------

#define N_NODES 50000
#define N_EDGES 500000
#define N_GRAPHS 64
#define IN_DIM 6
#define GNN_DIM 1024
#define OUT_DIM 256
#define CAT_DIM 2048
#define M_PAD 50176   // 392 * 128  (392 = 8 XCDs * 49 row-groups)

typedef __attribute__((ext_vector_type(8))) short short8;
typedef __attribute__((ext_vector_type(4))) float f32x4;

// ---------------- static device scratch (allocated at module load) ---------
__device__ int g_cnt[N_NODES + 1];
__device__ int g_cursor[N_NODES];
__device__ int g_gcnt[N_GRAPHS];
__device__ int g_rowptr[N_NODES + 1];
__device__ int g_goff[N_GRAPHS + 1];
__device__ int g_esrc[N_EDGES];
__device__ __attribute__((aligned(256))) unsigned short g_w2lt[(size_t)GNN_DIM * GNN_DIM];
__device__ __attribute__((aligned(256))) unsigned short g_w2rt[(size_t)GNN_DIM * GNN_DIM];
__device__ float g_agg1[(size_t)N_NODES * IN_DIM];
__device__ __attribute__((aligned(256))) unsigned short g_h[(size_t)M_PAD * GNN_DIM];
__device__ __attribute__((aligned(256))) unsigned short g_agg2[(size_t)M_PAD * GNN_DIM];
__device__ __attribute__((aligned(256))) unsigned short g_h2[(size_t)M_PAD * GNN_DIM];
__device__ float g_lnsum[M_PAD];
__device__ float g_lnsq[M_PAD];
__device__ float g_gpool[(size_t)N_GRAPHS * CAT_DIM];

__device__ __forceinline__ float bflo(int u) { return __uint_as_float(((unsigned)u) << 16); }
__device__ __forceinline__ float bfhi(int u) { return __uint_as_float(((unsigned)u) & 0xffff0000u); }
__device__ __forceinline__ unsigned short f2bf(float f) {
    unsigned u = __float_as_uint(f);
    unsigned rounded = u + 0x7fff + ((u >> 16) & 1);   // RNE
    return (unsigned short)(rounded >> 16);
}
__device__ __forceinline__ int pack2(unsigned short a, unsigned short b) {
    return (int)((unsigned)a | ((unsigned)b << 16));
}

// ---------------------------------------------------------------------------
// zero + CSR build
// ---------------------------------------------------------------------------
__global__ void zero_kernel() {          // grid 512 -> 131072 threads
    int i = blockIdx.x * 256 + threadIdx.x;
    if (i <= N_NODES) g_cnt[i] = 0;
    if (i < N_NODES) g_cursor[i] = 0;
    if (i < N_GRAPHS) g_gcnt[i] = 0;
    if (i < M_PAD) { g_lnsum[i] = 0.f; g_lnsq[i] = 0.f; }
    if (i < N_GRAPHS * CAT_DIM) g_gpool[i] = 0.f;
}

__global__ void count_kernel(const int* __restrict__ dst, const int* __restrict__ batch) {
    int i = blockIdx.x * 256 + threadIdx.x;
    if (i < N_EDGES) atomicAdd(&g_cnt[dst[i]], 1);
    if (i < N_NODES) atomicAdd(&g_gcnt[batch[i]], 1);
}

// two-level scan: thread-serial chunk sums + wave shfl scan + cross-wave
__global__ __launch_bounds__(1024) void scan_kernel() {
    const int CH = 49;           // 1024 * 49 = 50176 >= N_NODES+1
    int t = threadIdx.x;
    int base = t * CH;
    int s = 0;
    #pragma unroll
    for (int i = 0; i < CH; ++i) {
        int n = base + i;
        s += (n < N_NODES) ? g_cnt[n] : 0;
    }
    int lane = t & 63, w = t >> 6;
    int x = s;
    #pragma unroll
    for (int off = 1; off < 64; off <<= 1) {
        int y = __shfl_up(x, off);
        if (lane >= off) x += y;
    }
    __shared__ int wsum[16], woff[16];
    if (lane == 63) wsum[w] = x;
    __syncthreads();
    if (t == 0) { int a = 0; for (int i = 0; i < 16; ++i) { woff[i] = a; a += wsum[i]; } }
    __syncthreads();
    int excl = x - s + woff[w];      // exclusive prefix at chunk start
    #pragma unroll
    for (int i = 0; i < CH; ++i) {
        int n = base + i;
        if (n <= N_NODES) g_rowptr[n] = excl;
        if (n < N_NODES) excl += g_cnt[n];
    }
}

__global__ void goff_kernel() {
    if (threadIdx.x == 0 && blockIdx.x == 0) {
        int acc = 0;
        for (int g = 0; g < N_GRAPHS; ++g) { g_goff[g] = acc; acc += g_gcnt[g]; }
        g_goff[N_GRAPHS] = acc;
    }
}

__global__ void scatter_kernel(const int* __restrict__ src, const int* __restrict__ dst) {
    int e = blockIdx.x * 256 + threadIdx.x;
    if (e >= N_EDGES) return;
    int d = dst[e];
    int pos = atomicAdd(&g_cursor[d], 1);
    g_esrc[g_rowptr[d] + pos] = src[e];
}

// ---------------------------------------------------------------------------
// Weight transpose f32 [K][N] -> bf16 [N][K]
// ---------------------------------------------------------------------------
__global__ void transpose_bf16(const float* __restrict__ W, unsigned short* __restrict__ Wt) {
    __shared__ float tile[32][33];
    int bx = blockIdx.x & 31, by = blockIdx.x >> 5;
    int tx = threadIdx.x & 31, ty = threadIdx.x >> 5;  // 32x8
    for (int i = 0; i < 32; i += 8)
        tile[ty + i][tx] = W[(size_t)(by * 32 + ty + i) * GNN_DIM + bx * 32 + tx];
    __syncthreads();
    for (int i = 0; i < 32; i += 8)
        Wt[(size_t)(bx * 32 + ty + i) * GNN_DIM + by * 32 + tx] = f2bf(tile[tx][ty + i]);
}

// ---------------------------------------------------------------------------
// Layer 1: mean-agg of x (6-dim), transform, LN, ReLU -> h (bf16)
// ---------------------------------------------------------------------------
__global__ void l1_agg_kernel(const float* __restrict__ x) {
    int id = blockIdx.x * 256 + threadIdx.x;
    int n = id >> 3, slot = id & 7;
    if (n >= N_NODES || slot >= IN_DIM) return;
    int beg = g_rowptr[n], end = g_rowptr[n + 1];
    float s = 0.f;
    for (int i = beg; i < end; ++i) s += x[(size_t)g_esrc[i] * IN_DIM + slot];
    g_agg1[n * IN_DIM + slot] = s / (float)max(end - beg, 1);
}

// 8 nodes per block; weights held in registers (dims t*4..t*4+3 per thread)
__global__ __launch_bounds__(256) void l1_transform_kernel(
        const float* __restrict__ x,
        const float* __restrict__ W1l, const float* __restrict__ b1,
        const float* __restrict__ W1r, const float* __restrict__ g1,
        const float* __restrict__ be1) {
    int t = threadIdx.x;
    int nb = blockIdx.x * 8;                 // 6250 blocks * 8 = 50000 exact
    float4 wl[6], wr[6];
    #pragma unroll
    for (int k = 0; k < 6; ++k) {
        wl[k] = *(const float4*)&W1l[k * GNN_DIM + t * 4];
        wr[k] = *(const float4*)&W1r[k * GNN_DIM + t * 4];
    }
    float4 bb = *(const float4*)&b1[t * 4];
    float4 gg = *(const float4*)&g1[t * 4];
    float4 be = *(const float4*)&be1[t * 4];
    __shared__ float sx[48], sa[48];
    if (t < 48) sx[t] = x[nb * 6 + t];
    else if (t < 96) sa[t - 48] = g_agg1[nb * 6 + (t - 48)];
    __syncthreads();
    __shared__ float s1[4], s2[4];
    for (int u = 0; u < 8; ++u) {
        int n = nb + u;
        float4 v = bb;
        #pragma unroll
        for (int k = 0; k < 6; ++k) {
            float a = sa[u * 6 + k], xx = sx[u * 6 + k];
            v.x += a * wl[k].x + xx * wr[k].x;
            v.y += a * wl[k].y + xx * wr[k].y;
            v.z += a * wl[k].z + xx * wr[k].z;
            v.w += a * wl[k].w + xx * wr[k].w;
        }
        float sum = v.x + v.y + v.z + v.w;
        float sq  = v.x*v.x + v.y*v.y + v.z*v.z + v.w*v.w;
        #pragma unroll
        for (int off = 32; off; off >>= 1) { sum += __shfl_xor(sum, off); sq += __shfl_xor(sq, off); }
        if ((t & 63) == 0) { s1[t >> 6] = sum; s2[t >> 6] = sq; }
        __syncthreads();
        sum = s1[0] + s1[1] + s1[2] + s1[3];
        sq  = s2[0] + s2[1] + s2[2] + s2[3];
        __syncthreads();
        float mu = sum * (1.f / GNN_DIM);
        float var = sq * (1.f / GNN_DIM) - mu * mu;
        float rstd = rsqrtf(var + 1e-5f);
        float y0 = fmaxf((v.x - mu) * rstd * gg.x + be.x, 0.f);
        float y1 = fmaxf((v.y - mu) * rstd * gg.y + be.y, 0.f);
        float y2 = fmaxf((v.z - mu) * rstd * gg.z + be.z, 0.f);
        float y3 = fmaxf((v.w - mu) * rstd * gg.w + be.w, 0.f);
        int2 pk;
        pk.x = pack2(f2bf(y0), f2bf(y1));
        pk.y = pack2(f2bf(y2), f2bf(y3));
        *(int2*)(g_h + (size_t)n * GNN_DIM + t * 4) = pk;
    }
}

// ---------------------------------------------------------------------------
// Layer 2 aggregation: agg2[n] = mean of h[src] rows.
// Half-row per wave (1 int4/lane), 2 waves/node, masked 8-edge batches
// -> 8 independent 1KB requests in flight per wave (latency -> BW bound).
// ---------------------------------------------------------------------------
__global__ __launch_bounds__(256) void l2_agg_kernel() {
    int w = threadIdx.x >> 6, lane = threadIdx.x & 63;
    int n = blockIdx.x * 2 + (w >> 1);       // 25000 blocks * 2 = 50000 exact
    int hw = w & 1;
    int beg = g_rowptr[n], end = g_rowptr[n + 1];
    float s[8];
    #pragma unroll
    for (int j = 0; j < 8; ++j) s[j] = 0.f;
    const int4* hp = (const int4*)g_h;       // row = 128 int4
    int off = hw * 64 + lane;
    for (int i = beg; i < end; i += 8) {
        int idx[8]; float msk[8]; int4 v[8];
        #pragma unroll
        for (int j = 0; j < 8; ++j) {
            int e = i + j;
            int cl = (e < end) ? e : beg;    // beg valid since loop entered
            idx[j] = g_esrc[cl];
            msk[j] = (e < end) ? 1.f : 0.f;
        }
        #pragma unroll
        for (int j = 0; j < 8; ++j) v[j] = hp[(size_t)idx[j] * 128 + off];
        #pragma unroll
        for (int j = 0; j < 8; ++j) {
            float m = msk[j];
            s[0] += m * bflo(v[j].x); s[1] += m * bfhi(v[j].x);
            s[2] += m * bflo(v[j].y); s[3] += m * bfhi(v[j].y);
            s[4] += m * bflo(v[j].z); s[5] += m * bfhi(v[j].z);
            s[6] += m * bflo(v[j].w); s[7] += m * bfhi(v[j].w);
        }
    }
    float inv = 1.f / (float)max(end - beg, 1);
    int4 o;
    o.x = pack2(f2bf(s[0] * inv), f2bf(s[1] * inv));
    o.y = pack2(f2bf(s[2] * inv), f2bf(s[3] * inv));
    o.z = pack2(f2bf(s[4] * inv), f2bf(s[5] * inv));
    o.w = pack2(f2bf(s[6] * inv), f2bf(s[7] * inv));
    *(int4*)(g_agg2 + (size_t)n * GNN_DIM + (size_t)off * 8) = o;
}

// ---------------------------------------------------------------------------
// Layer 2 GEMM: h2 = agg2 @ W2_l + h @ W2_r + b2  (bf16 MFMA)
// XCD-bijective tile remap + XOR swizzle. Epilogue also accumulates per-row
// LN partial sums (sum, sumsq) via 16-lane butterfly + atomicAdd.
// ---------------------------------------------------------------------------
#define BM 128
#define BN 128
#define BK 64

__global__ __launch_bounds__(256) void gemm2_kernel(const float* __restrict__ bias) {
    __shared__ __attribute__((aligned(16))) unsigned short As[BM * BK];
    __shared__ __attribute__((aligned(16))) unsigned short Bs[BN * BK];
    int i = blockIdx.x;
    int xcd = i & 7;
    int j = i >> 3;                 // 0..391
    int bm = xcd * 49 + (j >> 3);   // 0..391
    int bn = j & 7;
    int row0 = bm * BM, col0 = bn * BN;
    int t = threadIdx.x;
    int lane = t & 63, wid = t >> 6;
    int wr = wid >> 1, wc = wid & 1;     // 2x2 waves, each owns 64x64
    f32x4 acc[4][4] = {};
    int c0 = t;
    for (int seg = 0; seg < 2; ++seg) {
        const unsigned short* A  = seg ? g_h : g_agg2;
        const unsigned short* Bt = seg ? g_w2rt : g_w2lt;
        for (int k0 = 0; k0 < GNN_DIM; k0 += BK) {
            __syncthreads();
            #pragma unroll
            for (int u = 0; u < 4; ++u) {
                int c = c0 + u * 256;
                int r = c >> 3;
                int kb = (c & 7) * 16;                  // byte offset within row
                int kbs = kb ^ ((r & 7) << 4);          // inverse-swizzled source
                __builtin_amdgcn_global_load_lds(
                    (const __attribute__((address_space(1))) void*)(A + (size_t)(row0 + r) * GNN_DIM + k0 + (kbs >> 1)),
                    (__attribute__((address_space(3))) void*)(As + c * 8), 16, 0, 0);
            }
            #pragma unroll
            for (int u = 0; u < 4; ++u) {
                int c = c0 + u * 256;
                int r = c >> 3;
                int kb = (c & 7) * 16;
                int kbs = kb ^ ((r & 7) << 4);
                __builtin_amdgcn_global_load_lds(
                    (const __attribute__((address_space(1))) void*)(Bt + (size_t)(col0 + r) * GNN_DIM + k0 + (kbs >> 1)),
                    (__attribute__((address_space(3))) void*)(Bs + c * 8), 16, 0, 0);
            }
            asm volatile("s_waitcnt vmcnt(0)" ::: "memory");
            __syncthreads();
            #pragma unroll
            for (int kk = 0; kk < BK; kk += 32) {
                short8 a[4], b[4];
                int krd = kk + (lane >> 4) * 8;          // short index in row
                #pragma unroll
                for (int m = 0; m < 4; ++m) {
                    int row = wr * 64 + m * 16 + (lane & 15);
                    int ks = ((krd * 2) ^ ((row & 7) << 4)) >> 1;   // swizzled read
                    a[m] = *(const short8*)&As[row * BK + ks];
                }
                #pragma unroll
                for (int n = 0; n < 4; ++n) {
                    int row = wc * 64 + n * 16 + (lane & 15);
                    int ks = ((krd * 2) ^ ((row & 7) << 4)) >> 1;
                    b[n] = *(const short8*)&Bs[row * BK + ks];
                }
                #pragma unroll
                for (int m = 0; m < 4; ++m)
                    #pragma unroll
                    for (int n = 0; n < 4; ++n)
                        acc[m][n] = __builtin_amdgcn_mfma_f32_16x16x32_bf16(a[m], b[n], acc[m][n], 0, 0, 0);
            }
        }
    }
    // epilogue: bias, bf16 write, per-row LN partial stats
    #pragma unroll
    for (int m = 0; m < 4; ++m) {
        float rs[4] = {0.f, 0.f, 0.f, 0.f}, rq[4] = {0.f, 0.f, 0.f, 0.f};
        int rbase = row0 + wr * 64 + m * 16 + (lane >> 4) * 4;
        #pragma unroll
        for (int n = 0; n < 4; ++n) {
            int col = col0 + wc * 64 + n * 16 + (lane & 15);
            float bv = bias[col];
            #pragma unroll
            for (int r = 0; r < 4; ++r) {
                float v = acc[m][n][r] + bv;
                g_h2[(size_t)(rbase + r) * GNN_DIM + col] = f2bf(v);
                rs[r] += v; rq[r] += v * v;
            }
        }
        #pragma unroll
        for (int r = 0; r < 4; ++r) {
            float a = rs[r], b = rq[r];
            #pragma unroll
            for (int mk = 1; mk < 16; mk <<= 1) { a += __shfl_xor(a, mk); b += __shfl_xor(b, mk); }
            if ((lane & 15) == 0) {
                atomicAdd(&g_lnsum[rbase + r], a);
                atomicAdd(&g_lnsq[rbase + r], b);
            }
        }
    }
}

// ---------------------------------------------------------------------------
// Pool (h part): apply LN+ReLU on the fly from h2 + stats, accumulate per
// graph. grid = 64 graphs * 8 node-slices; thread owns 4 dims.
// ---------------------------------------------------------------------------
__global__ __launch_bounds__(256) void pool_h_kernel(const float* __restrict__ g2,
                                                     const float* __restrict__ be2) {
    int g = blockIdx.x >> 3, sl = blockIdx.x & 7;
    int t = threadIdx.x;
    int beg = g_goff[g], end = g_goff[g + 1];
    int cnt = end - beg;
    int per = (cnt + 7) >> 3;
    int s0 = beg + sl * per, s1 = min(s0 + per, end);
    if (s0 >= s1) return;
    float4 gg = *(const float4*)&g2[t * 4];
    float4 be = *(const float4*)&be2[t * 4];
    float a0 = 0.f, a1 = 0.f, a2 = 0.f, a3 = 0.f;
    for (int n = s0; n < s1; ++n) {
        float mu = g_lnsum[n] * (1.f / GNN_DIM);
        float var = g_lnsq[n] * (1.f / GNN_DIM) - mu * mu;
        float rstd = rsqrtf(var + 1e-5f);
        int2 w = *(const int2*)(g_h2 + (size_t)n * GNN_DIM + t * 4);
        a0 += fmaxf((bflo(w.x) - mu) * rstd * gg.x + be.x, 0.f);
        a1 += fmaxf((bfhi(w.x) - mu) * rstd * gg.y + be.y, 0.f);
        a2 += fmaxf((bflo(w.y) - mu) * rstd * gg.z + be.z, 0.f);
        a3 += fmaxf((bfhi(w.y) - mu) * rstd * gg.w + be.w, 0.f);
    }
    atomicAdd(&g_gpool[g * CAT_DIM + t * 4 + 0], a0);
    atomicAdd(&g_gpool[g * CAT_DIM + t * 4 + 1], a1);
    atomicAdd(&g_gpool[g * CAT_DIM + t * 4 + 2], a2);
    atomicAdd(&g_gpool[g * CAT_DIM + t * 4 + 3], a3);
}

// ---------------------------------------------------------------------------
// Pool (fourier part): coords staged in LDS; thread handles 2 (scale,c)
// pairs, one proj shared by sin+cos. grid = 64 graphs * 2 node-slices.
// ---------------------------------------------------------------------------
__global__ __launch_bounds__(256) void pool_f_kernel(const float* __restrict__ coords,
                                                     const float* __restrict__ Bmat) {
    int g = blockIdx.x >> 1, sl = blockIdx.x & 1;
    int t = threadIdx.x;
    int beg = g_goff[g], end = g_goff[g + 1];
    int cnt = end - beg;
    int per = (cnt + 1) >> 1;
    int s0 = beg + sl * per, s1 = min(s0 + per, end);
    const float SC[4] = {1.f, 5.f, 10.f, 30.f};
    int si0 = t >> 7, c0 = t & 127;        // scales 0,1
    int si1 = si0 + 2;                     // scales 2,3
    float b00 = Bmat[c0] * SC[si0], b01 = Bmat[128 + c0] * SC[si0], b02 = Bmat[256 + c0] * SC[si0];
    float b10 = Bmat[c0] * SC[si1], b11 = Bmat[128 + c0] * SC[si1], b12 = Bmat[256 + c0] * SC[si1];
    float ss0 = 0.f, cs0 = 0.f, ss1 = 0.f, cs1 = 0.f;
    __shared__ float sc[256 * 3];
    for (int base = s0; base < s1; base += 256) {
        int m = min(256, s1 - base);
        __syncthreads();
        for (int q = t; q < 3 * m; q += 256) sc[q] = coords[base * 3 + q];
        __syncthreads();
        for (int i = 0; i < m; ++i) {
            float x0 = sc[i * 3], y0 = sc[i * 3 + 1], z0 = sc[i * 3 + 2];
            float p0 = x0 * b00 + y0 * b01 + z0 * b02;
            float p1 = x0 * b10 + y0 * b11 + z0 * b12;
            ss0 += __sinf(p0); cs0 += __cosf(p0);
            ss1 += __sinf(p1); cs1 += __cosf(p1);
        }
    }
    if (s0 < s1) {
        float* gp = g_gpool + g * CAT_DIM + GNN_DIM;
        atomicAdd(&gp[si0 * 256 + c0], ss0);
        atomicAdd(&gp[si0 * 256 + 128 + c0], cs0);
        atomicAdd(&gp[si1 * 256 + c0], ss1);
        atomicAdd(&gp[si1 * 256 + 128 + c0], cs1);
    }
}

// ---------------------------------------------------------------------------
// Final: out = LN(gpool/cnt @ Wfc + bfc)   (64 blocks x 256 threads)
// ---------------------------------------------------------------------------
__global__ __launch_bounds__(256) void final_kernel(
        const float* __restrict__ Wfc, const float* __restrict__ bfc,
        const float* __restrict__ gfc, const float* __restrict__ befc,
        float* __restrict__ out) {
    int g = blockIdx.x, t = threadIdx.x;
    int beg = g_goff[g], end = g_goff[g + 1];
    float inv = 1.f / (float)max(end - beg, 1);
    __shared__ float hg[CAT_DIM];
    for (int i = t; i < CAT_DIM; i += 256) hg[i] = g_gpool[g * CAT_DIM + i] * inv;
    __syncthreads();
    float acc = bfc[t];
    for (int k = 0; k < CAT_DIM; ++k) acc = fmaf(hg[k], Wfc[(size_t)k * OUT_DIM + t], acc);
    float sum = acc, sq = acc * acc;
    #pragma unroll
    for (int off = 32; off; off >>= 1) { sum += __shfl_xor(sum, off); sq += __shfl_xor(sq, off); }
    __shared__ float s1[4], s2[4];
    if ((t & 63) == 0) { s1[t >> 6] = sum; s2[t >> 6] = sq; }
    __syncthreads();
    sum = s1[0] + s1[1] + s1[2] + s1[3];
    sq  = s2[0] + s2[1] + s2[2] + s2[3];
    float mu = sum * (1.f / OUT_DIM);
    float var = sq * (1.f / OUT_DIM) - mu * mu;
    float rstd = rsqrtf(var + 1e-5f);
    out[g * OUT_DIM + t] = (acc - mu) * rstd * gfc[t] + befc[t];
}

// ---------------------------------------------------------------------------
extern "C" void kernel_launch(void* const* d_in, const int* in_sizes, int n_in,
                              void* d_out, int out_size, void* d_ws, size_t ws_size,
                              hipStream_t stream) {
    const float* x      = (const float*)d_in[0];
    const int*   ei     = (const int*)d_in[1];
    const float* coords = (const float*)d_in[2];
    const int*   batch  = (const int*)d_in[3];
    const float* Bmat   = (const float*)d_in[4];
    const float* W1l    = (const float*)d_in[5];
    const float* b1     = (const float*)d_in[6];
    const float* W1r    = (const float*)d_in[7];
    const float* g1     = (const float*)d_in[8];
    const float* be1    = (const float*)d_in[9];
    const float* W2l    = (const float*)d_in[10];
    const float* b2     = (const float*)d_in[11];
    const float* W2r    = (const float*)d_in[12];
    const float* g2     = (const float*)d_in[13];
    const float* be2    = (const float*)d_in[14];
    const float* Wfc    = (const float*)d_in[15];
    const float* bfc    = (const float*)d_in[16];
    const float* gfc    = (const float*)d_in[17];
    const float* befc   = (const float*)d_in[18];
    const int* src = ei;
    const int* dst = ei + N_EDGES;
    float* out = (float*)d_out;
    (void)in_sizes; (void)n_in; (void)out_size; (void)d_ws; (void)ws_size;

    unsigned short* w2lt;  hipGetSymbolAddress((void**)&w2lt, HIP_SYMBOL(g_w2lt));
    unsigned short* w2rt;  hipGetSymbolAddress((void**)&w2rt, HIP_SYMBOL(g_w2rt));

    zero_kernel<<<512, 256, 0, stream>>>();
    count_kernel<<<(N_EDGES + 255) / 256, 256, 0, stream>>>(dst, batch);
    scan_kernel<<<1, 1024, 0, stream>>>();
    goff_kernel<<<1, 64, 0, stream>>>();
    scatter_kernel<<<(N_EDGES + 255) / 256, 256, 0, stream>>>(src, dst);

    transpose_bf16<<<1024, 256, 0, stream>>>(W2l, w2lt);
    transpose_bf16<<<1024, 256, 0, stream>>>(W2r, w2rt);

    l1_agg_kernel<<<(N_NODES * 8 + 255) / 256, 256, 0, stream>>>(x);
    l1_transform_kernel<<<N_NODES / 8, 256, 0, stream>>>(x, W1l, b1, W1r, g1, be1);

    l2_agg_kernel<<<N_NODES / 2, 256, 0, stream>>>();

    gemm2_kernel<<<(M_PAD / BM) * (GNN_DIM / BN), 256, 0, stream>>>(b2);

    pool_h_kernel<<<N_GRAPHS * 8, 256, 0, stream>>>(g2, be2);
    pool_f_kernel<<<N_GRAPHS * 2, 256, 0, stream>>>(coords, Bmat);

    final_kernel<<<N_GRAPHS, 256, 0, stream>>>(Wfc, bfc, gfc, befc, out);
}

// Round 6
// 895.473 us; speedup vs baseline: 1.5362x; 1.0129x over previous
//
#include <hip/hip_runtime.h>
#include <hip/hip_bf16.h>

// ---------------------------------------------------------------------------
// GraphEncoder: SAGE(6->1024) -> LN -> ReLU -> SAGE(1024->1024) -> LN -> ReLU
//   -> concat(Fourier feats) -> per-graph mean pool -> FC(2048->256) -> LN
// ---------------------------------------------------------------------------

#define N_NODES 50000
#define N_EDGES 500000
#define N_GRAPHS 64
#define IN_DIM 6
#define GNN_DIM 1024
#define OUT_DIM 256
#define CAT_DIM 2048
#define M_PAD 50176   // 392 * 128  (392 = 8 XCDs * 49 row-groups)

typedef __attribute__((ext_vector_type(8))) short short8;
typedef __attribute__((ext_vector_type(4))) float f32x4;

// ---------------- static device scratch (allocated at module load) ---------
__device__ int g_cnt[N_NODES + 1];
__device__ int g_cursor[N_NODES];
__device__ int g_gcnt[N_GRAPHS];
__device__ int g_rowptr[N_NODES + 1];
__device__ int g_goff[N_GRAPHS + 1];
__device__ int g_esrc[N_EDGES];
__device__ __attribute__((aligned(256))) unsigned short g_w2lt[(size_t)GNN_DIM * GNN_DIM];
__device__ __attribute__((aligned(256))) unsigned short g_w2rt[(size_t)GNN_DIM * GNN_DIM];
__device__ float g_agg1[(size_t)N_NODES * IN_DIM];
__device__ __attribute__((aligned(256))) unsigned short g_h[(size_t)M_PAD * GNN_DIM];
__device__ __attribute__((aligned(256))) unsigned short g_agg2[(size_t)M_PAD * GNN_DIM];
__device__ __attribute__((aligned(256))) unsigned short g_h2[(size_t)M_PAD * GNN_DIM];
__device__ float g_gpool[(size_t)N_GRAPHS * CAT_DIM];

__device__ __forceinline__ float bflo(int u) { return __uint_as_float(((unsigned)u) << 16); }
__device__ __forceinline__ float bfhi(int u) { return __uint_as_float(((unsigned)u) & 0xffff0000u); }
__device__ __forceinline__ unsigned short f2bf(float f) {
    unsigned u = __float_as_uint(f);
    unsigned rounded = u + 0x7fff + ((u >> 16) & 1);   // RNE
    return (unsigned short)(rounded >> 16);
}
__device__ __forceinline__ int pack2(unsigned short a, unsigned short b) {
    return (int)((unsigned)a | ((unsigned)b << 16));
}

// ---------------------------------------------------------------------------
// zero + CSR build
// ---------------------------------------------------------------------------
__global__ void zero_kernel() {          // grid 512 -> 131072 threads
    int i = blockIdx.x * 256 + threadIdx.x;
    if (i <= N_NODES) g_cnt[i] = 0;
    if (i < N_NODES) g_cursor[i] = 0;
    if (i < N_GRAPHS) g_gcnt[i] = 0;
    if (i < N_GRAPHS * CAT_DIM) g_gpool[i] = 0.f;
}

__global__ void count_kernel(const int* __restrict__ dst, const int* __restrict__ batch) {
    int i = blockIdx.x * 256 + threadIdx.x;
    if (i < N_EDGES) atomicAdd(&g_cnt[dst[i]], 1);
    if (i < N_NODES) atomicAdd(&g_gcnt[batch[i]], 1);
}

// two-level scan: thread-serial chunk sums + wave shfl scan + cross-wave
__global__ __launch_bounds__(1024) void scan_kernel() {
    const int CH = 49;           // 1024 * 49 = 50176 >= N_NODES+1
    int t = threadIdx.x;
    int base = t * CH;
    int s = 0;
    #pragma unroll
    for (int i = 0; i < CH; ++i) {
        int n = base + i;
        s += (n < N_NODES) ? g_cnt[n] : 0;
    }
    int lane = t & 63, w = t >> 6;
    int x = s;
    #pragma unroll
    for (int off = 1; off < 64; off <<= 1) {
        int y = __shfl_up(x, off);
        if (lane >= off) x += y;
    }
    __shared__ int wsum[16], woff[16];
    if (lane == 63) wsum[w] = x;
    __syncthreads();
    if (t == 0) { int a = 0; for (int i = 0; i < 16; ++i) { woff[i] = a; a += wsum[i]; } }
    __syncthreads();
    int excl = x - s + woff[w];      // exclusive prefix at chunk start
    #pragma unroll
    for (int i = 0; i < CH; ++i) {
        int n = base + i;
        if (n <= N_NODES) g_rowptr[n] = excl;
        if (n < N_NODES) excl += g_cnt[n];
    }
}

__global__ void goff_kernel() {
    if (threadIdx.x == 0 && blockIdx.x == 0) {
        int acc = 0;
        for (int g = 0; g < N_GRAPHS; ++g) { g_goff[g] = acc; acc += g_gcnt[g]; }
        g_goff[N_GRAPHS] = acc;
    }
}

__global__ void scatter_kernel(const int* __restrict__ src, const int* __restrict__ dst) {
    int e = blockIdx.x * 256 + threadIdx.x;
    if (e >= N_EDGES) return;
    int d = dst[e];
    int pos = atomicAdd(&g_cursor[d], 1);
    g_esrc[g_rowptr[d] + pos] = src[e];
}

// ---------------------------------------------------------------------------
// Weight transpose f32 [K][N] -> bf16 [N][K], both weights in one dispatch
// ---------------------------------------------------------------------------
__global__ void transpose_bf16(const float* __restrict__ WA, const float* __restrict__ WB,
                               unsigned short* __restrict__ TA, unsigned short* __restrict__ TB) {
    __shared__ float tile[32][33];
    int id = blockIdx.x & 1023;
    const float* W = (blockIdx.x >> 10) ? WB : WA;
    unsigned short* Wt = (blockIdx.x >> 10) ? TB : TA;
    int bx = id & 31, by = id >> 5;
    int tx = threadIdx.x & 31, ty = threadIdx.x >> 5;  // 32x8
    for (int i = 0; i < 32; i += 8)
        tile[ty + i][tx] = W[(size_t)(by * 32 + ty + i) * GNN_DIM + bx * 32 + tx];
    __syncthreads();
    for (int i = 0; i < 32; i += 8)
        Wt[(size_t)(bx * 32 + ty + i) * GNN_DIM + by * 32 + tx] = f2bf(tile[tx][ty + i]);
}

// ---------------------------------------------------------------------------
// Layer 1: mean-agg of x (6-dim), transform, LN, ReLU -> h (bf16)
// ---------------------------------------------------------------------------
__global__ void l1_agg_kernel(const float* __restrict__ x) {
    int id = blockIdx.x * 256 + threadIdx.x;
    int n = id >> 3, slot = id & 7;
    if (n >= N_NODES || slot >= IN_DIM) return;
    int beg = g_rowptr[n], end = g_rowptr[n + 1];
    float s = 0.f;
    for (int i = beg; i < end; ++i) s += x[(size_t)g_esrc[i] * IN_DIM + slot];
    g_agg1[n * IN_DIM + slot] = s / (float)max(end - beg, 1);
}

// 8 nodes per block; weights held in registers (dims t*4..t*4+3 per thread)
__global__ __launch_bounds__(256) void l1_transform_kernel(
        const float* __restrict__ x,
        const float* __restrict__ W1l, const float* __restrict__ b1,
        const float* __restrict__ W1r, const float* __restrict__ g1,
        const float* __restrict__ be1) {
    int t = threadIdx.x;
    int nb = blockIdx.x * 8;                 // 6250 blocks * 8 = 50000 exact
    float4 wl[6], wr[6];
    #pragma unroll
    for (int k = 0; k < 6; ++k) {
        wl[k] = *(const float4*)&W1l[k * GNN_DIM + t * 4];
        wr[k] = *(const float4*)&W1r[k * GNN_DIM + t * 4];
    }
    float4 bb = *(const float4*)&b1[t * 4];
    float4 gg = *(const float4*)&g1[t * 4];
    float4 be = *(const float4*)&be1[t * 4];
    __shared__ float sx[48], sa[48];
    if (t < 48) sx[t] = x[nb * 6 + t];
    else if (t < 96) sa[t - 48] = g_agg1[nb * 6 + (t - 48)];
    __syncthreads();
    __shared__ float s1[4], s2[4];
    for (int u = 0; u < 8; ++u) {
        int n = nb + u;
        float4 v = bb;
        #pragma unroll
        for (int k = 0; k < 6; ++k) {
            float a = sa[u * 6 + k], xx = sx[u * 6 + k];
            v.x += a * wl[k].x + xx * wr[k].x;
            v.y += a * wl[k].y + xx * wr[k].y;
            v.z += a * wl[k].z + xx * wr[k].z;
            v.w += a * wl[k].w + xx * wr[k].w;
        }
        float sum = v.x + v.y + v.z + v.w;
        float sq  = v.x*v.x + v.y*v.y + v.z*v.z + v.w*v.w;
        #pragma unroll
        for (int off = 32; off; off >>= 1) { sum += __shfl_xor(sum, off); sq += __shfl_xor(sq, off); }
        if ((t & 63) == 0) { s1[t >> 6] = sum; s2[t >> 6] = sq; }
        __syncthreads();
        sum = s1[0] + s1[1] + s1[2] + s1[3];
        sq  = s2[0] + s2[1] + s2[2] + s2[3];
        __syncthreads();
        float mu = sum * (1.f / GNN_DIM);
        float var = sq * (1.f / GNN_DIM) - mu * mu;
        float rstd = rsqrtf(var + 1e-5f);
        float y0 = fmaxf((v.x - mu) * rstd * gg.x + be.x, 0.f);
        float y1 = fmaxf((v.y - mu) * rstd * gg.y + be.y, 0.f);
        float y2 = fmaxf((v.z - mu) * rstd * gg.z + be.z, 0.f);
        float y3 = fmaxf((v.w - mu) * rstd * gg.w + be.w, 0.f);
        int2 pk;
        pk.x = pack2(f2bf(y0), f2bf(y1));
        pk.y = pack2(f2bf(y2), f2bf(y3));
        *(int2*)(g_h + (size_t)n * GNN_DIM + t * 4) = pk;
    }
}

// ---------------------------------------------------------------------------
// Layer 2 aggregation: agg2[n] = mean of h[src] rows.
// Full row per wave (2 int4/lane), masked 8-edge batches -> 16 independent
// 1KB requests in flight per wave.
// ---------------------------------------------------------------------------
__global__ __launch_bounds__(256) void l2_agg_kernel() {
    int w = threadIdx.x >> 6, lane = threadIdx.x & 63;
    int n = blockIdx.x * 4 + w;              // 12500 blocks * 4 = 50000 exact
    int beg = g_rowptr[n], end = g_rowptr[n + 1];
    float s[16];
    #pragma unroll
    for (int j = 0; j < 16; ++j) s[j] = 0.f;
    const int4* hp = (const int4*)g_h;       // row = 128 int4
    for (int i = beg; i < end; i += 8) {
        int idx[8]; float msk[8]; int4 va[8], vb[8];
        #pragma unroll
        for (int j = 0; j < 8; ++j) {
            int e = i + j;
            int cl = (e < end) ? e : beg;    // beg valid since loop entered
            idx[j] = g_esrc[cl];
            msk[j] = (e < end) ? 1.f : 0.f;
        }
        #pragma unroll
        for (int j = 0; j < 8; ++j) {
            va[j] = hp[(size_t)idx[j] * 128 + lane];
            vb[j] = hp[(size_t)idx[j] * 128 + 64 + lane];
        }
        #pragma unroll
        for (int j = 0; j < 8; ++j) {
            float m = msk[j];
            s[0]  += m * bflo(va[j].x); s[1]  += m * bfhi(va[j].x);
            s[2]  += m * bflo(va[j].y); s[3]  += m * bfhi(va[j].y);
            s[4]  += m * bflo(va[j].z); s[5]  += m * bfhi(va[j].z);
            s[6]  += m * bflo(va[j].w); s[7]  += m * bfhi(va[j].w);
            s[8]  += m * bflo(vb[j].x); s[9]  += m * bfhi(vb[j].x);
            s[10] += m * bflo(vb[j].y); s[11] += m * bfhi(vb[j].y);
            s[12] += m * bflo(vb[j].z); s[13] += m * bfhi(vb[j].z);
            s[14] += m * bflo(vb[j].w); s[15] += m * bfhi(vb[j].w);
        }
    }
    float inv = 1.f / (float)max(end - beg, 1);
    int4 o0, o1;
    o0.x = pack2(f2bf(s[0] * inv),  f2bf(s[1] * inv));
    o0.y = pack2(f2bf(s[2] * inv),  f2bf(s[3] * inv));
    o0.z = pack2(f2bf(s[4] * inv),  f2bf(s[5] * inv));
    o0.w = pack2(f2bf(s[6] * inv),  f2bf(s[7] * inv));
    o1.x = pack2(f2bf(s[8] * inv),  f2bf(s[9] * inv));
    o1.y = pack2(f2bf(s[10] * inv), f2bf(s[11] * inv));
    o1.z = pack2(f2bf(s[12] * inv), f2bf(s[13] * inv));
    o1.w = pack2(f2bf(s[14] * inv), f2bf(s[15] * inv));
    *(int4*)(g_agg2 + (size_t)n * GNN_DIM + (size_t)lane * 8) = o0;
    *(int4*)(g_agg2 + (size_t)n * GNN_DIM + 512 + (size_t)lane * 8) = o1;
}

// ---------------------------------------------------------------------------
// Layer 2 GEMM: h2 = agg2 @ W2_l + h @ W2_r + b2  (bf16 MFMA)
// XCD-bijective tile remap + XOR swizzle; clean bias+store epilogue.
// ---------------------------------------------------------------------------
#define BM 128
#define BN 128
#define BK 64

__global__ __launch_bounds__(256) void gemm2_kernel(const float* __restrict__ bias) {
    __shared__ __attribute__((aligned(16))) unsigned short As[BM * BK];
    __shared__ __attribute__((aligned(16))) unsigned short Bs[BN * BK];
    int i = blockIdx.x;
    int xcd = i & 7;
    int j = i >> 3;                 // 0..391
    int bm = xcd * 49 + (j >> 3);   // 0..391
    int bn = j & 7;
    int row0 = bm * BM, col0 = bn * BN;
    int t = threadIdx.x;
    int lane = t & 63, wid = t >> 6;
    int wr = wid >> 1, wc = wid & 1;     // 2x2 waves, each owns 64x64
    f32x4 acc[4][4] = {};
    int c0 = t;
    for (int seg = 0; seg < 2; ++seg) {
        const unsigned short* A  = seg ? g_h : g_agg2;
        const unsigned short* Bt = seg ? g_w2rt : g_w2lt;
        for (int k0 = 0; k0 < GNN_DIM; k0 += BK) {
            __syncthreads();
            #pragma unroll
            for (int u = 0; u < 4; ++u) {
                int c = c0 + u * 256;
                int r = c >> 3;
                int kb = (c & 7) * 16;                  // byte offset within row
                int kbs = kb ^ ((r & 7) << 4);          // inverse-swizzled source
                __builtin_amdgcn_global_load_lds(
                    (const __attribute__((address_space(1))) void*)(A + (size_t)(row0 + r) * GNN_DIM + k0 + (kbs >> 1)),
                    (__attribute__((address_space(3))) void*)(As + c * 8), 16, 0, 0);
            }
            #pragma unroll
            for (int u = 0; u < 4; ++u) {
                int c = c0 + u * 256;
                int r = c >> 3;
                int kb = (c & 7) * 16;
                int kbs = kb ^ ((r & 7) << 4);
                __builtin_amdgcn_global_load_lds(
                    (const __attribute__((address_space(1))) void*)(Bt + (size_t)(col0 + r) * GNN_DIM + k0 + (kbs >> 1)),
                    (__attribute__((address_space(3))) void*)(Bs + c * 8), 16, 0, 0);
            }
            asm volatile("s_waitcnt vmcnt(0)" ::: "memory");
            __syncthreads();
            #pragma unroll
            for (int kk = 0; kk < BK; kk += 32) {
                short8 a[4], b[4];
                int krd = kk + (lane >> 4) * 8;          // short index in row
                #pragma unroll
                for (int m = 0; m < 4; ++m) {
                    int row = wr * 64 + m * 16 + (lane & 15);
                    int ks = ((krd * 2) ^ ((row & 7) << 4)) >> 1;   // swizzled read
                    a[m] = *(const short8*)&As[row * BK + ks];
                }
                #pragma unroll
                for (int n = 0; n < 4; ++n) {
                    int row = wc * 64 + n * 16 + (lane & 15);
                    int ks = ((krd * 2) ^ ((row & 7) << 4)) >> 1;
                    b[n] = *(const short8*)&Bs[row * BK + ks];
                }
                #pragma unroll
                for (int m = 0; m < 4; ++m)
                    #pragma unroll
                    for (int n = 0; n < 4; ++n)
                        acc[m][n] = __builtin_amdgcn_mfma_f32_16x16x32_bf16(a[m], b[n], acc[m][n], 0, 0, 0);
            }
        }
    }
    #pragma unroll
    for (int m = 0; m < 4; ++m) {
        #pragma unroll
        for (int n = 0; n < 4; ++n) {
            int col = col0 + wc * 64 + n * 16 + (lane & 15);
            int rbase = row0 + wr * 64 + m * 16 + (lane >> 4) * 4;
            float bv = bias[col];
            #pragma unroll
            for (int r = 0; r < 4; ++r) {
                float v = acc[m][n][r] + bv;
                g_h2[(size_t)(rbase + r) * GNN_DIM + col] = f2bf(v);
            }
        }
    }
}

// ---------------------------------------------------------------------------
// Pool (h part): per node compute LN stats in-block (block sees full row),
// apply LN+ReLU, accumulate per graph. grid = 64 graphs * 8 node-slices.
// Next-row prefetch hides L3 latency across the per-node barriers.
// ---------------------------------------------------------------------------
__global__ __launch_bounds__(256) void pool_h_kernel(const float* __restrict__ g2,
                                                     const float* __restrict__ be2) {
    int g = blockIdx.x >> 3, sl = blockIdx.x & 7;
    int t = threadIdx.x;
    int beg = g_goff[g], end = g_goff[g + 1];
    int cnt = end - beg;
    int per = (cnt + 7) >> 3;
    int s0 = beg + sl * per, s1v = min(s0 + per, end);
    if (s0 >= s1v) return;                   // block-uniform
    float4 gg = *(const float4*)&g2[t * 4];
    float4 be = *(const float4*)&be2[t * 4];
    __shared__ float r1[4], r2[4];
    float a0 = 0.f, a1 = 0.f, a2 = 0.f, a3 = 0.f;
    int2 wv = *(const int2*)(g_h2 + (size_t)s0 * GNN_DIM + t * 4);
    for (int n = s0; n < s1v; ++n) {
        int2 w = wv;
        if (n + 1 < s1v) wv = *(const int2*)(g_h2 + (size_t)(n + 1) * GNN_DIM + t * 4);
        float v0 = bflo(w.x), v1 = bfhi(w.x), v2 = bflo(w.y), v3 = bfhi(w.y);
        float sum = v0 + v1 + v2 + v3;
        float sq  = v0*v0 + v1*v1 + v2*v2 + v3*v3;
        #pragma unroll
        for (int off = 32; off; off >>= 1) { sum += __shfl_xor(sum, off); sq += __shfl_xor(sq, off); }
        if ((t & 63) == 0) { r1[t >> 6] = sum; r2[t >> 6] = sq; }
        __syncthreads();
        sum = r1[0] + r1[1] + r1[2] + r1[3];
        sq  = r2[0] + r2[1] + r2[2] + r2[3];
        __syncthreads();
        float mu = sum * (1.f / GNN_DIM);
        float var = sq * (1.f / GNN_DIM) - mu * mu;
        float rstd = rsqrtf(var + 1e-5f);
        a0 += fmaxf((v0 - mu) * rstd * gg.x + be.x, 0.f);
        a1 += fmaxf((v1 - mu) * rstd * gg.y + be.y, 0.f);
        a2 += fmaxf((v2 - mu) * rstd * gg.z + be.z, 0.f);
        a3 += fmaxf((v3 - mu) * rstd * gg.w + be.w, 0.f);
    }
    atomicAdd(&g_gpool[g * CAT_DIM + t * 4 + 0], a0);
    atomicAdd(&g_gpool[g * CAT_DIM + t * 4 + 1], a1);
    atomicAdd(&g_gpool[g * CAT_DIM + t * 4 + 2], a2);
    atomicAdd(&g_gpool[g * CAT_DIM + t * 4 + 3], a3);
}

// ---------------------------------------------------------------------------
// Pool (fourier part): coords staged in LDS; thread handles 2 (scale,c)
// pairs, one proj shared by sin+cos. grid = 64 graphs * 2 node-slices.
// ---------------------------------------------------------------------------
__global__ __launch_bounds__(256) void pool_f_kernel(const float* __restrict__ coords,
                                                     const float* __restrict__ Bmat) {
    int g = blockIdx.x >> 1, sl = blockIdx.x & 1;
    int t = threadIdx.x;
    int beg = g_goff[g], end = g_goff[g + 1];
    int cnt = end - beg;
    int per = (cnt + 1) >> 1;
    int s0 = beg + sl * per, s1 = min(s0 + per, end);
    const float SC[4] = {1.f, 5.f, 10.f, 30.f};
    int si0 = t >> 7, c0 = t & 127;        // scales 0,1
    int si1 = si0 + 2;                     // scales 2,3
    float b00 = Bmat[c0] * SC[si0], b01 = Bmat[128 + c0] * SC[si0], b02 = Bmat[256 + c0] * SC[si0];
    float b10 = Bmat[c0] * SC[si1], b11 = Bmat[128 + c0] * SC[si1], b12 = Bmat[256 + c0] * SC[si1];
    float ss0 = 0.f, cs0 = 0.f, ss1 = 0.f, cs1 = 0.f;
    __shared__ float sc[256 * 3];
    for (int base = s0; base < s1; base += 256) {
        int m = min(256, s1 - base);
        __syncthreads();
        for (int q = t; q < 3 * m; q += 256) sc[q] = coords[base * 3 + q];
        __syncthreads();
        for (int i = 0; i < m; ++i) {
            float x0 = sc[i * 3], y0 = sc[i * 3 + 1], z0 = sc[i * 3 + 2];
            float p0 = x0 * b00 + y0 * b01 + z0 * b02;
            float p1 = x0 * b10 + y0 * b11 + z0 * b12;
            ss0 += __sinf(p0); cs0 += __cosf(p0);
            ss1 += __sinf(p1); cs1 += __cosf(p1);
        }
    }
    if (s0 < s1) {
        float* gp = g_gpool + g * CAT_DIM + GNN_DIM;
        atomicAdd(&gp[si0 * 256 + c0], ss0);
        atomicAdd(&gp[si0 * 256 + 128 + c0], cs0);
        atomicAdd(&gp[si1 * 256 + c0], ss1);
        atomicAdd(&gp[si1 * 256 + 128 + c0], cs1);
    }
}

// ---------------------------------------------------------------------------
// Final: out = LN(gpool/cnt @ Wfc + bfc)   (64 blocks x 256 threads)
// ---------------------------------------------------------------------------
__global__ __launch_bounds__(256) void final_kernel(
        const float* __restrict__ Wfc, const float* __restrict__ bfc,
        const float* __restrict__ gfc, const float* __restrict__ befc,
        float* __restrict__ out) {
    int g = blockIdx.x, t = threadIdx.x;
    int beg = g_goff[g], end = g_goff[g + 1];
    float inv = 1.f / (float)max(end - beg, 1);
    __shared__ float hg[CAT_DIM];
    for (int i = t; i < CAT_DIM; i += 256) hg[i] = g_gpool[g * CAT_DIM + i] * inv;
    __syncthreads();
    float acc = bfc[t];
    for (int k = 0; k < CAT_DIM; ++k) acc = fmaf(hg[k], Wfc[(size_t)k * OUT_DIM + t], acc);
    float sum = acc, sq = acc * acc;
    #pragma unroll
    for (int off = 32; off; off >>= 1) { sum += __shfl_xor(sum, off); sq += __shfl_xor(sq, off); }
    __shared__ float s1[4], s2[4];
    if ((t & 63) == 0) { s1[t >> 6] = sum; s2[t >> 6] = sq; }
    __syncthreads();
    sum = s1[0] + s1[1] + s1[2] + s1[3];
    sq  = s2[0] + s2[1] + s2[2] + s2[3];
    float mu = sum * (1.f / OUT_DIM);
    float var = sq * (1.f / OUT_DIM) - mu * mu;
    float rstd = rsqrtf(var + 1e-5f);
    out[g * OUT_DIM + t] = (acc - mu) * rstd * gfc[t] + befc[t];
}

// ---------------------------------------------------------------------------
extern "C" void kernel_launch(void* const* d_in, const int* in_sizes, int n_in,
                              void* d_out, int out_size, void* d_ws, size_t ws_size,
                              hipStream_t stream) {
    const float* x      = (const float*)d_in[0];
    const int*   ei     = (const int*)d_in[1];
    const float* coords = (const float*)d_in[2];
    const int*   batch  = (const int*)d_in[3];
    const float* Bmat   = (const float*)d_in[4];
    const float* W1l    = (const float*)d_in[5];
    const float* b1     = (const float*)d_in[6];
    const float* W1r    = (const float*)d_in[7];
    const float* g1     = (const float*)d_in[8];
    const float* be1    = (const float*)d_in[9];
    const float* W2l    = (const float*)d_in[10];
    const float* b2     = (const float*)d_in[11];
    const float* W2r    = (const float*)d_in[12];
    const float* g2     = (const float*)d_in[13];
    const float* be2    = (const float*)d_in[14];
    const float* Wfc    = (const float*)d_in[15];
    const float* bfc    = (const float*)d_in[16];
    const float* gfc    = (const float*)d_in[17];
    const float* befc   = (const float*)d_in[18];
    const int* src = ei;
    const int* dst = ei + N_EDGES;
    float* out = (float*)d_out;
    (void)in_sizes; (void)n_in; (void)out_size; (void)d_ws; (void)ws_size;

    unsigned short* w2lt;  hipGetSymbolAddress((void**)&w2lt, HIP_SYMBOL(g_w2lt));
    unsigned short* w2rt;  hipGetSymbolAddress((void**)&w2rt, HIP_SYMBOL(g_w2rt));

    zero_kernel<<<512, 256, 0, stream>>>();
    count_kernel<<<(N_EDGES + 255) / 256, 256, 0, stream>>>(dst, batch);
    scan_kernel<<<1, 1024, 0, stream>>>();
    goff_kernel<<<1, 64, 0, stream>>>();
    scatter_kernel<<<(N_EDGES + 255) / 256, 256, 0, stream>>>(src, dst);

    transpose_bf16<<<2048, 256, 0, stream>>>(W2l, W2r, w2lt, w2rt);

    l1_agg_kernel<<<(N_NODES * 8 + 255) / 256, 256, 0, stream>>>(x);
    l1_transform_kernel<<<N_NODES / 8, 256, 0, stream>>>(x, W1l, b1, W1r, g1, be1);

    l2_agg_kernel<<<N_NODES / 4, 256, 0, stream>>>();

    gemm2_kernel<<<(M_PAD / BM) * (GNN_DIM / BN), 256, 0, stream>>>(b2);

    pool_h_kernel<<<N_GRAPHS * 8, 256, 0, stream>>>(g2, be2);
    pool_f_kernel<<<N_GRAPHS * 2, 256, 0, stream>>>(coords, Bmat);

    final_kernel<<<N_GRAPHS, 256, 0, stream>>>(Wfc, bfc, gfc, befc, out);
}